// Round 1
// baseline (188.428 us; speedup 1.0000x reference)
//
#include <hip/hip_runtime.h>
#include <hip/hip_bf16.h>

// ---------------- workspace layout (bytes) ----------------
// counts[4] @ 0, cursors[4] @ 64, bases[4] @ 128
// pos_map int[65536] @ 1024
// W_sku bf16[512][384] @ 263168
// W_url bf16[512][192] @ 656384   (cols 160..192 zero)
// W_qry bf16[512][192] @ 852992
// X arena bf16[(65536+128)][384] @ 1049600  (row stride 768 B; +128 rows slack
//   so partial-tile staging reads never run off the arena)
#define CNT_OFF   0
#define CUR_OFF   64
#define BASE_OFF  128
#define POS_OFF   1024
#define WSKU_OFF  263168
#define WURL_OFF  656384
#define WQRY_OFF  852992
#define X_OFF     1049600
// total need: 1049600 + 65664*768 = 51,479,552 bytes (~49.1 MB)

#define NPOS      65536          // B*S
#define OUT_MASK  33554432       // 65536*512

typedef __attribute__((ext_vector_type(8))) short bf16x8;
typedef __attribute__((ext_vector_type(4))) float f32x4;

__device__ __forceinline__ unsigned short f2bf(float x) {
    unsigned int u = __float_as_uint(x);
    unsigned int r = (u + 0x7fffu + ((u >> 16) & 1u)) >> 16;   // RNE
    return (unsigned short)r;
}
__device__ __forceinline__ void st2(__hip_bfloat16* d, float2 v) {
    unsigned int pk = (unsigned int)f2bf(v.x) | ((unsigned int)f2bf(v.y) << 16);
    *reinterpret_cast<unsigned int*>(d) = pk;
}
__device__ __forceinline__ float2 ld2(const float* p) {
    return *reinterpret_cast<const float2*>(p);
}

#define AS1(p) ((const __attribute__((address_space(1))) void*)(p))
#define AS3(p) ((__attribute__((address_space(3))) void*)(p))

// ---------------- K1: branch counts (ballot-aggregated) ----------------
__global__ __launch_bounds__(256) void count_k(const int* __restrict__ et_a, char* ws) {
    int p = blockIdx.x * 256 + threadIdx.x;
    int lane = threadIdx.x & 63;
    int et = et_a[p];
    int br = (et >= 1 && et <= 3) ? 0 : (et == 4 ? 1 : (et == 5 ? 2 : -1));
    unsigned long long m0 = __ballot(br == 0);
    unsigned long long m1 = __ballot(br == 1);
    unsigned long long m2 = __ballot(br == 2);
    if (lane == 0) {
        int* c = (int*)(ws + CNT_OFF);
        if (m0) atomicAdd(&c[0], (int)__popcll(m0));
        if (m1) atomicAdd(&c[1], (int)__popcll(m1));
        if (m2) atomicAdd(&c[2], (int)__popcll(m2));
    }
}

// ---------------- K2: bases + cursors ----------------
__global__ void bases_k(char* ws) {
    int* c   = (int*)(ws + CNT_OFF);
    int* cur = (int*)(ws + CUR_OFF);
    int* b   = (int*)(ws + BASE_OFF);
    int c0 = c[0], c1 = c[1];
    b[0] = 0; b[1] = c0; b[2] = c0 + c1;
    cur[0] = 0; cur[1] = c0; cur[2] = c0 + c1;
}

// ---------------- K4: weight f32 -> bf16 (url/query padded to K=192) --------
__global__ __launch_bounds__(256) void wcvt_k(const float* __restrict__ sw,
                                              const float* __restrict__ uw,
                                              const float* __restrict__ qw,
                                              char* ws) {
    int t = blockIdx.x * 256 + threadIdx.x;   // 393216 total
    if (t < 196608) {
        ((unsigned short*)(ws + WSKU_OFF))[t] = f2bf(sw[t]);
    } else if (t < 294912) {
        int i = t - 196608; int n = i / 192, k = i % 192;
        ((unsigned short*)(ws + WURL_OFF))[i] = (k < 160) ? f2bf(uw[n * 160 + k]) : 0;
    } else if (t < 393216) {
        int i = t - 294912; int n = i / 192, k = i % 192;
        ((unsigned short*)(ws + WQRY_OFF))[i] = (k < 160) ? f2bf(qw[n * 160 + k]) : 0;
    }
}

// ---------------- K3: build compacted bf16 input rows ----------------
__device__ __forceinline__ float2 wmean(const float* __restrict__ wt,
                                        const int* __restrict__ wids, int lane) {
    float sx = 0.f, sy = 0.f;
    #pragma unroll
    for (int k = 0; k < 12; ++k) {
        const float* r = wt + (size_t)wids[k] * 128;
        float2 v = ld2(r + 2 * lane);
        sx += v.x; sy += v.y;
    }
    const float inv = 1.0f / 12.0f;
    return make_float2(sx * inv, sy * inv);
}

__global__ __launch_bounds__(256) void build_k(
    const float* __restrict__ ev_t,   const float* __restrict__ word_t,
    const float* __restrict__ sku_t,  const float* __restrict__ cat_t,
    const float* __restrict__ price_t,const float* __restrict__ url_t,
    const int* __restrict__ et_a,     const int* __restrict__ sku_id,
    const int* __restrict__ url_id,   const int* __restrict__ cat_id,
    const int* __restrict__ price_id, const int* __restrict__ word_id,
    float* __restrict__ out, char* ws)
{
    __shared__ int s_slot[64];
    __shared__ int s_et[64];
    const int t = threadIdx.x, lane = t & 63, wid = t >> 6;
    const int p0 = blockIdx.x * 64;
    int* cur  = (int*)(ws + CUR_OFF);
    int* posm = (int*)(ws + POS_OFF);

    if (wid == 0) {   // classification + slot allocation (one wave, 64 positions)
        int p = p0 + lane;
        int et = et_a[p];
        int br = (et >= 1 && et <= 3) ? 0 : (et == 4 ? 1 : (et == 5 ? 2 : -1));
        unsigned long long m0 = __ballot(br == 0);
        unsigned long long m1 = __ballot(br == 1);
        unsigned long long m2 = __ballot(br == 2);
        int b0 = 0, b1 = 0, b2 = 0;
        if (lane == 0) {
            if (m0) b0 = atomicAdd(&cur[0], (int)__popcll(m0));
            if (m1) b1 = atomicAdd(&cur[1], (int)__popcll(m1));
            if (m2) b2 = atomicAdd(&cur[2], (int)__popcll(m2));
        }
        b0 = __shfl(b0, 0); b1 = __shfl(b1, 0); b2 = __shfl(b2, 0);
        unsigned long long lt = (1ull << lane) - 1ull;
        int slot = -1;
        if (br == 0) slot = b0 + (int)__popcll(m0 & lt);
        else if (br == 1) slot = b1 + (int)__popcll(m1 & lt);
        else if (br == 2) slot = b2 + (int)__popcll(m2 & lt);
        s_slot[lane] = slot; s_et[lane] = et;
        if (slot >= 0) posm[slot] = p;
        out[OUT_MASK + p] = (et == 0) ? 1.0f : 0.0f;
    }
    __syncthreads();

    for (int i = wid; i < 64; i += 4) {
        int p = p0 + i;
        int et = s_et[i], slot = s_slot[i];
        if (et == 0) {  // pad: zero output row
            float4 z = {0.f, 0.f, 0.f, 0.f};
            float* orow = out + (size_t)p * 512;
            *reinterpret_cast<float4*>(&orow[lane * 8])     = z;
            *reinterpret_cast<float4*>(&orow[lane * 8 + 4]) = z;
            continue;
        }
        if (slot < 0) continue;
        __hip_bfloat16* X = (__hip_bfloat16*)(ws + X_OFF + (size_t)slot * 768);
        const float* evr = ev_t + et * 32;
        if (et <= 3) {  // sku: [ev 0..32)[sku 32..160)[cat 160..224)[price 224..256)[word 256..384)
            if (lane < 16) st2(X + 2 * lane, ld2(evr + 2 * lane));
            const float* sr = sku_t + (size_t)sku_id[p] * 128;
            st2(X + 32 + 2 * lane, ld2(sr + 2 * lane));
            const float* crr = cat_t + (size_t)cat_id[p] * 64;
            if (lane < 32) st2(X + 160 + 2 * lane, ld2(crr + 2 * lane));
            const float* prr = price_t + (size_t)price_id[p] * 32;
            if (lane < 16) st2(X + 224 + 2 * lane, ld2(prr + 2 * lane));
            float2 w = wmean(word_t, word_id + (size_t)p * 12, lane);
            st2(X + 256 + 2 * lane, w);
        } else if (et == 4) {  // url: [url 0..128)[ev 128..160)[pad 160..192)
            const float* ur = url_t + (size_t)url_id[p] * 128;
            st2(X + 2 * lane, ld2(ur + 2 * lane));
            if (lane < 16) st2(X + 128 + 2 * lane, ld2(evr + 2 * lane));
            if (lane < 16) st2(X + 160 + 2 * lane, make_float2(0.f, 0.f));
        } else {               // query: [ev 0..32)[word 32..160)[pad 160..192)
            if (lane < 16) st2(X + 2 * lane, ld2(evr + 2 * lane));
            float2 w = wmean(word_t, word_id + (size_t)p * 12, lane);
            st2(X + 32 + 2 * lane, w);
            if (lane < 16) st2(X + 160 + 2 * lane, make_float2(0.f, 0.f));
        }
    }
}

// ---------------- K5-7: branch GEMM  out[pos] = relu(X * W^T + b) ------------
// 128x128 tile, BK=64, 4 waves (2x2) x 64x64, mfma_f32_16x16x32_bf16.
// T2 swizzle: LDS linear dest, source pre-swizzled, reads XOR'd (rule #21).
template<int NKT, int WSTRIDE>
__global__ __launch_bounds__(256, 2) void gemm_k(
    const char* __restrict__ arena,   // ws + X_OFF (row stride 768 B)
    const char* __restrict__ Wb,      // bf16 weight arena, row stride WSTRIDE B
    const float* __restrict__ bias,   // [512]
    const int* __restrict__ cntp,     // this branch's count
    const int* __restrict__ basep,    // this branch's base slot
    const int* __restrict__ posm,     // pos_map (全) — index base+row
    float* __restrict__ out)
{
    const int count = *cntp;
    const int mt = blockIdx.x;
    if (mt * 128 >= count) return;
    const int base = *basep;
    const int row0 = mt * 128;
    const int nc0  = blockIdx.y * 128;

    __shared__ char lds[2][2][16384];   // [buf][A/B][128 rows x 128 B]

    const int t = threadIdx.x;
    const int lane = t & 63;
    const int wid  = t >> 6;
    const int wr = wid >> 1, wc = wid & 1;
    const int r = lane & 15, q = lane >> 4;

    auto stage = [&](int buf, int kt) {
        #pragma unroll
        for (int i = 0; i < 4; ++i) {
            int row = i * 32 + (t >> 3);
            int sb  = (t & 7) ^ (row & 7);
            const char* ga = arena + (size_t)(base + row0 + row) * 768 + kt * 128 + sb * 16;
            __builtin_amdgcn_global_load_lds(AS1(ga), AS3(&lds[buf][0][i * 4096 + t * 16]), 16, 0, 0);
            const char* gb = Wb + (size_t)(nc0 + row) * WSTRIDE + kt * 128 + sb * 16;
            __builtin_amdgcn_global_load_lds(AS1(gb), AS3(&lds[buf][1][i * 4096 + t * 16]), 16, 0, 0);
        }
    };

    f32x4 acc[4][4];
    #pragma unroll
    for (int m = 0; m < 4; ++m)
        #pragma unroll
        for (int n = 0; n < 4; ++n)
            acc[m][n] = (f32x4){0.f, 0.f, 0.f, 0.f};

    stage(0, 0);
    __syncthreads();
    int cur = 0;
    for (int kt = 0; kt < NKT; ++kt) {
        if (kt + 1 < NKT) stage(cur ^ 1, kt + 1);
        #pragma unroll
        for (int kk = 0; kk < 2; ++kk) {
            bf16x8 af[4], bfr[4];
            #pragma unroll
            for (int m = 0; m < 4; ++m) {
                int arow = wr * 64 + m * 16 + r;
                af[m] = *reinterpret_cast<const bf16x8*>(
                    &lds[cur][0][arow * 128 + (((kk * 4 + q) ^ (r & 7)) * 16)]);
            }
            #pragma unroll
            for (int n = 0; n < 4; ++n) {
                int brow = wc * 64 + n * 16 + r;
                bfr[n] = *reinterpret_cast<const bf16x8*>(
                    &lds[cur][1][brow * 128 + (((kk * 4 + q) ^ (r & 7)) * 16)]);
            }
            #pragma unroll
            for (int m = 0; m < 4; ++m)
                #pragma unroll
                for (int n = 0; n < 4; ++n)
                    acc[m][n] = __builtin_amdgcn_mfma_f32_16x16x32_bf16(af[m], bfr[n], acc[m][n], 0, 0, 0);
        }
        __syncthreads();
        cur ^= 1;
    }

    // epilogue: relu(acc + bias), scatter rows via pos_map
    float bv[4];
    #pragma unroll
    for (int n = 0; n < 4; ++n) bv[n] = bias[nc0 + wc * 64 + n * 16 + r];
    #pragma unroll
    for (int m = 0; m < 4; ++m) {
        #pragma unroll
        for (int j = 0; j < 4; ++j) {
            int rl = wr * 64 + m * 16 + q * 4 + j;
            int gr = row0 + rl;
            if (gr < count) {
                int pos = posm[base + gr];
                float* orow = out + (size_t)pos * 512 + nc0 + wc * 64;
                #pragma unroll
                for (int n = 0; n < 4; ++n)
                    orow[n * 16 + r] = fmaxf(acc[m][n][j] + bv[n], 0.f);
            }
        }
    }
}

// ---------------- host ----------------
extern "C" void kernel_launch(void* const* d_in, const int* in_sizes, int n_in,
                              void* d_out, int out_size, void* d_ws, size_t ws_size,
                              hipStream_t stream) {
    const float* ev_t    = (const float*)d_in[0];
    const float* word_t  = (const float*)d_in[1];
    const float* sku_t   = (const float*)d_in[2];
    const float* cat_t   = (const float*)d_in[3];
    const float* price_t = (const float*)d_in[4];
    const float* url_t   = (const float*)d_in[5];
    const float* sku_w   = (const float*)d_in[6];
    const float* sku_b   = (const float*)d_in[7];
    const float* url_w   = (const float*)d_in[8];
    const float* url_b   = (const float*)d_in[9];
    const float* query_w = (const float*)d_in[10];
    const float* query_b = (const float*)d_in[11];
    const int* event_type = (const int*)d_in[12];
    const int* sku_id     = (const int*)d_in[13];
    const int* url_id     = (const int*)d_in[14];
    const int* cat_id     = (const int*)d_in[15];
    const int* price_id   = (const int*)d_in[16];
    const int* word_id    = (const int*)d_in[17];

    char*  ws  = (char*)d_ws;
    float* out = (float*)d_out;

    hipMemsetAsync(ws + CNT_OFF, 0, 64, stream);                 // zero counts
    wcvt_k<<<1536, 256, 0, stream>>>(sku_w, url_w, query_w, ws);
    count_k<<<256, 256, 0, stream>>>(event_type, ws);
    bases_k<<<1, 1, 0, stream>>>(ws);
    build_k<<<1024, 256, 0, stream>>>(ev_t, word_t, sku_t, cat_t, price_t, url_t,
                                      event_type, sku_id, url_id, cat_id, price_id,
                                      word_id, out, ws);

    const int* cnt  = (const int*)(ws + CNT_OFF);
    const int* bas  = (const int*)(ws + BASE_OFF);
    const int* posm = (const int*)(ws + POS_OFF);
    const char* arena = ws + X_OFF;

    dim3 gg(512, 4);
    gemm_k<6, 768><<<gg, 256, 0, stream>>>(arena, ws + WSKU_OFF, sku_b,
                                           &cnt[0], &bas[0], posm, out);
    gemm_k<3, 384><<<gg, 256, 0, stream>>>(arena, ws + WURL_OFF, url_b,
                                           &cnt[1], &bas[1], posm, out);
    gemm_k<3, 384><<<gg, 256, 0, stream>>>(arena, ws + WQRY_OFF, query_b,
                                           &cnt[2], &bas[2], posm, out);
}

// Round 2
// 104.873 us; speedup vs baseline: 1.7967x; 1.7967x over previous
//
#include <hip/hip_runtime.h>
#include <hip/hip_bf16.h>

// ---------------- workspace layout (bytes); ws_size ~1 GB ----------------
#define CUR_OFF   0          // int cur[3]  (atomic cursors == final counts)
#define SLOT_OFF  1024       // int slot_of_pos[65536]
#define POS_OFF   263168     // int posm[3][65536]
#define WSKU_OFF  1049600    // bf16 [512][384]
#define WURL_OFF  1442816    // bf16 [512][192] (cols 160..192 zero)
#define WQRY_OFF  1639424    // bf16 [512][192]
#define XS_OFF    1836032    // bf16 rows, stride 768 B, 65664 rows
#define XU_OFF    52265984   // bf16 rows, stride 384 B, 65664 rows
#define XQ_OFF    77480960   // bf16 rows, stride 384 B, 65664 rows
// end ~102.7 MB  (ws poison fill showed ~1.024 GB available)

#define NPOS      65536
#define OUT_MASK  33554432   // 65536*512

typedef __attribute__((ext_vector_type(8))) short bf16x8;
typedef __attribute__((ext_vector_type(4))) float f32x4;

__device__ __forceinline__ unsigned short f2bf(float x) {
    unsigned int u = __float_as_uint(x);
    return (unsigned short)((u + 0x7fffu + ((u >> 16) & 1u)) >> 16);   // RNE
}
__device__ __forceinline__ void st2(__hip_bfloat16* d, float2 v) {
    unsigned int pk = (unsigned int)f2bf(v.x) | ((unsigned int)f2bf(v.y) << 16);
    *reinterpret_cast<unsigned int*>(d) = pk;
}
__device__ __forceinline__ float2 ld2(const float* p) {
    return *reinterpret_cast<const float2*>(p);
}

#define AS1(p) ((const __attribute__((address_space(1))) void*)(p))
#define AS3(p) ((__attribute__((address_space(3))) void*)(p))

// ---------------- K1: weight f32->bf16 + cursor zero ----------------
__global__ __launch_bounds__(256) void wcvt_k(const float* __restrict__ sw,
                                              const float* __restrict__ uw,
                                              const float* __restrict__ qw,
                                              char* ws) {
    int t = blockIdx.x * 256 + threadIdx.x;   // 393216 total
    if (t < 3) ((int*)(ws + CUR_OFF))[t] = 0;
    if (t < 196608) {
        ((unsigned short*)(ws + WSKU_OFF))[t] = f2bf(sw[t]);
    } else if (t < 294912) {
        int i = t - 196608; int n = i / 192, k = i % 192;
        ((unsigned short*)(ws + WURL_OFF))[i] = (k < 160) ? f2bf(uw[n * 160 + k]) : 0;
    } else if (t < 393216) {
        int i = t - 294912; int n = i / 192, k = i % 192;
        ((unsigned short*)(ws + WQRY_OFF))[i] = (k < 160) ? f2bf(qw[n * 160 + k]) : 0;
    }
}

// ---------------- K2: classify + slot allocation (block-aggregated) ----------
__global__ __launch_bounds__(256) void alloc_k(const int* __restrict__ et_a,
                                               float* __restrict__ out, char* ws) {
    __shared__ int s_wcnt[4][3];
    __shared__ int s_base[3];
    __shared__ int s_woff[4][3];
    const int t = threadIdx.x, lane = t & 63, wid = t >> 6;
    int p = blockIdx.x * 256 + t;
    int et = et_a[p];
    int br = (et >= 1 && et <= 3) ? 0 : (et == 4 ? 1 : (et == 5 ? 2 : -1));
    unsigned long long m0 = __ballot(br == 0);
    unsigned long long m1 = __ballot(br == 1);
    unsigned long long m2 = __ballot(br == 2);
    if (lane == 0) {
        s_wcnt[wid][0] = (int)__popcll(m0);
        s_wcnt[wid][1] = (int)__popcll(m1);
        s_wcnt[wid][2] = (int)__popcll(m2);
    }
    __syncthreads();
    if (t < 3) {
        int c0 = s_wcnt[0][t], c1 = s_wcnt[1][t], c2 = s_wcnt[2][t], c3 = s_wcnt[3][t];
        int tot = c0 + c1 + c2 + c3;
        s_base[t] = tot ? atomicAdd(&((int*)(ws + CUR_OFF))[t], tot) : 0;
        s_woff[0][t] = 0; s_woff[1][t] = c0; s_woff[2][t] = c0 + c1; s_woff[3][t] = c0 + c1 + c2;
    }
    __syncthreads();
    unsigned long long lt = (1ull << lane) - 1ull;
    int slot = -1;
    if (br == 0)      slot = s_base[0] + s_woff[wid][0] + (int)__popcll(m0 & lt);
    else if (br == 1) slot = s_base[1] + s_woff[wid][1] + (int)__popcll(m1 & lt);
    else if (br == 2) slot = s_base[2] + s_woff[wid][2] + (int)__popcll(m2 & lt);
    ((int*)(ws + SLOT_OFF))[p] = slot;
    if (slot >= 0) ((int*)(ws + POS_OFF))[br * NPOS + slot] = p;
    out[OUT_MASK + p] = (et == 0) ? 1.0f : 0.0f;
}

// ---------------- K3: build bf16 input rows, 1 position per wave ------------
__device__ __forceinline__ float2 wmean(const float* __restrict__ wt,
                                        const int* __restrict__ wids, int lane) {
    float sx = 0.f, sy = 0.f;
    #pragma unroll
    for (int k = 0; k < 12; ++k) {
        const float* r = wt + (size_t)wids[k] * 128;
        float2 v = ld2(r + 2 * lane);
        sx += v.x; sy += v.y;
    }
    const float inv = 1.0f / 12.0f;
    return make_float2(sx * inv, sy * inv);
}

__global__ __launch_bounds__(256) void build_k(
    const float* __restrict__ ev_t,   const float* __restrict__ word_t,
    const float* __restrict__ sku_t,  const float* __restrict__ cat_t,
    const float* __restrict__ price_t,const float* __restrict__ url_t,
    const int* __restrict__ et_a,     const int* __restrict__ sku_id,
    const int* __restrict__ url_id,   const int* __restrict__ cat_id,
    const int* __restrict__ price_id, const int* __restrict__ word_id,
    float* __restrict__ out, char* ws)
{
    const int t = threadIdx.x, lane = t & 63, wid = t >> 6;
    const int p = blockIdx.x * 4 + wid;         // one position per wave
    const int et = et_a[p];
    if (et == 0) {  // pad: zero output row
        float4 z = {0.f, 0.f, 0.f, 0.f};
        float* orow = out + (size_t)p * 512;
        *reinterpret_cast<float4*>(&orow[lane * 8])     = z;
        *reinterpret_cast<float4*>(&orow[lane * 8 + 4]) = z;
        return;
    }
    const int slot = ((const int*)(ws + SLOT_OFF))[p];
    const float* evr = ev_t + et * 32;
    if (et <= 3) {  // sku: [ev 0..32)[sku 32..160)[cat 160..224)[price 224..256)[word 256..384)
        __hip_bfloat16* X = (__hip_bfloat16*)(ws + XS_OFF + (size_t)slot * 768);
        if (lane < 16) st2(X + 2 * lane, ld2(evr + 2 * lane));
        const float* sr = sku_t + (size_t)sku_id[p] * 128;
        st2(X + 32 + 2 * lane, ld2(sr + 2 * lane));
        const float* crr = cat_t + (size_t)cat_id[p] * 64;
        if (lane < 32) st2(X + 160 + 2 * lane, ld2(crr + 2 * lane));
        const float* prr = price_t + (size_t)price_id[p] * 32;
        if (lane < 16) st2(X + 224 + 2 * lane, ld2(prr + 2 * lane));
        float2 w = wmean(word_t, word_id + (size_t)p * 12, lane);
        st2(X + 256 + 2 * lane, w);
    } else if (et == 4) {  // url: [url 0..128)[ev 128..160)[pad 160..192)
        __hip_bfloat16* X = (__hip_bfloat16*)(ws + XU_OFF + (size_t)slot * 384);
        const float* ur = url_t + (size_t)url_id[p] * 128;
        st2(X + 2 * lane, ld2(ur + 2 * lane));
        if (lane < 16) st2(X + 128 + 2 * lane, ld2(evr + 2 * lane));
        if (lane < 16) st2(X + 160 + 2 * lane, make_float2(0.f, 0.f));
    } else {               // query: [ev 0..32)[word 32..160)[pad 160..192)
        __hip_bfloat16* X = (__hip_bfloat16*)(ws + XQ_OFF + (size_t)slot * 384);
        if (lane < 16) st2(X + 2 * lane, ld2(evr + 2 * lane));
        float2 w = wmean(word_t, word_id + (size_t)p * 12, lane);
        st2(X + 32 + 2 * lane, w);
        if (lane < 16) st2(X + 160 + 2 * lane, make_float2(0.f, 0.f));
    }
}

// ---------------- K4: merged branch GEMMs  out[pos]=relu(X*W^T+b) -----------
// 128x128 tile, BK=64, 4 waves (2x2) x 64x64, mfma_f32_16x16x32_bf16.
// T2 swizzle: linear LDS dest, source pre-swizzled, reads XOR'd (rule #21).
__global__ __launch_bounds__(256, 2) void gemm_all_k(
    const char* __restrict__ ws_c, const float* __restrict__ sku_b,
    const float* __restrict__ url_b, const float* __restrict__ qry_b,
    float* __restrict__ out)
{
    const int z = blockIdx.z;
    const int count = ((const int*)(ws_c + CUR_OFF))[z];
    const int mt = blockIdx.x;
    if (mt * 128 >= count) return;
    const int row0 = mt * 128;
    const int nc0  = blockIdx.y * 128;

    const char* arena; const char* Wb; const float* bias; const int* posm;
    int astride, nkt;
    if (z == 0) { arena = ws_c + XS_OFF; Wb = ws_c + WSKU_OFF; bias = sku_b;
                  posm = (const int*)(ws_c + POS_OFF);          astride = 768; nkt = 6; }
    else if (z == 1) { arena = ws_c + XU_OFF; Wb = ws_c + WURL_OFF; bias = url_b;
                  posm = (const int*)(ws_c + POS_OFF) + NPOS;   astride = 384; nkt = 3; }
    else       { arena = ws_c + XQ_OFF; Wb = ws_c + WQRY_OFF; bias = qry_b;
                  posm = (const int*)(ws_c + POS_OFF) + 2*NPOS; astride = 384; nkt = 3; }
    const int wstride = astride;   // weight row bytes == X row bytes per branch

    __shared__ char lds[2][2][16384];   // [buf][A/B][128 rows x 128 B]

    const int t = threadIdx.x;
    const int lane = t & 63;
    const int wid  = t >> 6;
    const int wr = wid >> 1, wc = wid & 1;
    const int r = lane & 15, q = lane >> 4;

    auto stage = [&](int buf, int kt) {
        #pragma unroll
        for (int i = 0; i < 4; ++i) {
            int row = i * 32 + (t >> 3);
            int sb  = (t & 7) ^ (row & 7);
            const char* ga = arena + (size_t)(row0 + row) * astride + kt * 128 + sb * 16;
            __builtin_amdgcn_global_load_lds(AS1(ga), AS3(&lds[buf][0][i * 4096 + t * 16]), 16, 0, 0);
            const char* gb = Wb + (size_t)(nc0 + row) * wstride + kt * 128 + sb * 16;
            __builtin_amdgcn_global_load_lds(AS1(gb), AS3(&lds[buf][1][i * 4096 + t * 16]), 16, 0, 0);
        }
    };

    f32x4 acc[4][4];
    #pragma unroll
    for (int m = 0; m < 4; ++m)
        #pragma unroll
        for (int n = 0; n < 4; ++n)
            acc[m][n] = (f32x4){0.f, 0.f, 0.f, 0.f};

    stage(0, 0);
    __syncthreads();
    int cur = 0;
    for (int kt = 0; kt < nkt; ++kt) {
        if (kt + 1 < nkt) stage(cur ^ 1, kt + 1);
        #pragma unroll
        for (int kk = 0; kk < 2; ++kk) {
            bf16x8 af[4], bfr[4];
            #pragma unroll
            for (int m = 0; m < 4; ++m) {
                int arow = wr * 64 + m * 16 + r;
                af[m] = *reinterpret_cast<const bf16x8*>(
                    &lds[cur][0][arow * 128 + (((kk * 4 + q) ^ (r & 7)) * 16)]);
            }
            #pragma unroll
            for (int n = 0; n < 4; ++n) {
                int brow = wc * 64 + n * 16 + r;
                bfr[n] = *reinterpret_cast<const bf16x8*>(
                    &lds[cur][1][brow * 128 + (((kk * 4 + q) ^ (r & 7)) * 16)]);
            }
            #pragma unroll
            for (int m = 0; m < 4; ++m)
                #pragma unroll
                for (int n = 0; n < 4; ++n)
                    acc[m][n] = __builtin_amdgcn_mfma_f32_16x16x32_bf16(af[m], bfr[n], acc[m][n], 0, 0, 0);
        }
        __syncthreads();
        cur ^= 1;
    }

    float bv[4];
    #pragma unroll
    for (int n = 0; n < 4; ++n) bv[n] = bias[nc0 + wc * 64 + n * 16 + r];
    #pragma unroll
    for (int m = 0; m < 4; ++m) {
        #pragma unroll
        for (int j = 0; j < 4; ++j) {
            int rl = wr * 64 + m * 16 + q * 4 + j;
            int gr = row0 + rl;
            if (gr < count) {
                int pos = posm[gr];
                float* orow = out + (size_t)pos * 512 + nc0 + wc * 64;
                #pragma unroll
                for (int n = 0; n < 4; ++n)
                    orow[n * 16 + r] = fmaxf(acc[m][n][j] + bv[n], 0.f);
            }
        }
    }
}

// ---------------- host ----------------
extern "C" void kernel_launch(void* const* d_in, const int* in_sizes, int n_in,
                              void* d_out, int out_size, void* d_ws, size_t ws_size,
                              hipStream_t stream) {
    const float* ev_t    = (const float*)d_in[0];
    const float* word_t  = (const float*)d_in[1];
    const float* sku_t   = (const float*)d_in[2];
    const float* cat_t   = (const float*)d_in[3];
    const float* price_t = (const float*)d_in[4];
    const float* url_t   = (const float*)d_in[5];
    const float* sku_w   = (const float*)d_in[6];
    const float* sku_b   = (const float*)d_in[7];
    const float* url_w   = (const float*)d_in[8];
    const float* url_b   = (const float*)d_in[9];
    const float* query_w = (const float*)d_in[10];
    const float* query_b = (const float*)d_in[11];
    const int* event_type = (const int*)d_in[12];
    const int* sku_id     = (const int*)d_in[13];
    const int* url_id     = (const int*)d_in[14];
    const int* cat_id     = (const int*)d_in[15];
    const int* price_id   = (const int*)d_in[16];
    const int* word_id    = (const int*)d_in[17];

    char*  ws  = (char*)d_ws;
    float* out = (float*)d_out;

    wcvt_k<<<1536, 256, 0, stream>>>(sku_w, url_w, query_w, ws);
    alloc_k<<<256, 256, 0, stream>>>(event_type, out, ws);
    build_k<<<16384, 256, 0, stream>>>(ev_t, word_t, sku_t, cat_t, price_t, url_t,
                                       event_type, sku_id, url_id, cat_id, price_id,
                                       word_id, out, ws);
    dim3 gg(512, 4, 3);
    gemm_all_k<<<gg, 256, 0, stream>>>(ws, sku_b, url_b, query_b, out);
}

// Round 3
// 103.619 us; speedup vs baseline: 1.8185x; 1.0121x over previous
//
#include <hip/hip_runtime.h>
#include <hip/hip_bf16.h>

// ---------------- workspace layout (bytes); ws_size ~1 GB ----------------
#define CUR_OFF   0          // int cur[3]  (atomic cursors == final counts)
#define SLOT_OFF  1024       // int slot_of_pos[65536]
#define POS_OFF   263168     // int posm[3][65536]
#define WSKU_OFF  1049600    // bf16 [512][384]
#define WURL_OFF  1442816    // bf16 [512][192] (cols 160..192 zero)
#define WQRY_OFF  1639424    // bf16 [512][192]
#define XS_OFF    1836032    // bf16 rows, stride 768 B, 65664 rows
#define XU_OFF    52265984   // bf16 rows, stride 384 B, 65664 rows
#define XQ_OFF    77480960   // bf16 rows, stride 384 B, 65664 rows

#define NPOS      65536
#define OUT_MASK  33554432   // 65536*512

typedef __attribute__((ext_vector_type(8))) short bf16x8;
typedef __attribute__((ext_vector_type(4))) float f32x4;

__device__ __forceinline__ unsigned short f2bf(float x) {
    unsigned int u = __float_as_uint(x);
    return (unsigned short)((u + 0x7fffu + ((u >> 16) & 1u)) >> 16);   // RNE
}
__device__ __forceinline__ void st2(__hip_bfloat16* d, float2 v) {
    unsigned int pk = (unsigned int)f2bf(v.x) | ((unsigned int)f2bf(v.y) << 16);
    *reinterpret_cast<unsigned int*>(d) = pk;
}
__device__ __forceinline__ float2 ld2(const float* p) {
    return *reinterpret_cast<const float2*>(p);
}

#define AS1(p) ((const __attribute__((address_space(1))) void*)(p))
#define AS3(p) ((__attribute__((address_space(3))) void*)(p))

// ---------------- K1: weight f32->bf16 + cursor zero ----------------
__global__ __launch_bounds__(256) void wcvt_k(const float* __restrict__ sw,
                                              const float* __restrict__ uw,
                                              const float* __restrict__ qw,
                                              char* ws) {
    int t = blockIdx.x * 256 + threadIdx.x;   // 393216 total
    if (t < 3) ((int*)(ws + CUR_OFF))[t] = 0;
    if (t < 196608) {
        ((unsigned short*)(ws + WSKU_OFF))[t] = f2bf(sw[t]);
    } else if (t < 294912) {
        int i = t - 196608; int n = i / 192, k = i % 192;
        ((unsigned short*)(ws + WURL_OFF))[i] = (k < 160) ? f2bf(uw[n * 160 + k]) : 0;
    } else if (t < 393216) {
        int i = t - 294912; int n = i / 192, k = i % 192;
        ((unsigned short*)(ws + WQRY_OFF))[i] = (k < 160) ? f2bf(qw[n * 160 + k]) : 0;
    }
}

// ---------------- K2: classify + slot allocation (block-aggregated) ----------
__global__ __launch_bounds__(256) void alloc_k(const int* __restrict__ et_a,
                                               float* __restrict__ out, char* ws) {
    __shared__ int s_wcnt[4][3];
    __shared__ int s_base[3];
    __shared__ int s_woff[4][3];
    const int t = threadIdx.x, lane = t & 63, wid = t >> 6;
    int p = blockIdx.x * 256 + t;
    int et = et_a[p];
    int br = (et >= 1 && et <= 3) ? 0 : (et == 4 ? 1 : (et == 5 ? 2 : -1));
    unsigned long long m0 = __ballot(br == 0);
    unsigned long long m1 = __ballot(br == 1);
    unsigned long long m2 = __ballot(br == 2);
    if (lane == 0) {
        s_wcnt[wid][0] = (int)__popcll(m0);
        s_wcnt[wid][1] = (int)__popcll(m1);
        s_wcnt[wid][2] = (int)__popcll(m2);
    }
    __syncthreads();
    if (t < 3) {
        int c0 = s_wcnt[0][t], c1 = s_wcnt[1][t], c2 = s_wcnt[2][t], c3 = s_wcnt[3][t];
        int tot = c0 + c1 + c2 + c3;
        s_base[t] = tot ? atomicAdd(&((int*)(ws + CUR_OFF))[t], tot) : 0;
        s_woff[0][t] = 0; s_woff[1][t] = c0; s_woff[2][t] = c0 + c1; s_woff[3][t] = c0 + c1 + c2;
    }
    __syncthreads();
    unsigned long long lt = (1ull << lane) - 1ull;
    int slot = -1;
    if (br == 0)      slot = s_base[0] + s_woff[wid][0] + (int)__popcll(m0 & lt);
    else if (br == 1) slot = s_base[1] + s_woff[wid][1] + (int)__popcll(m1 & lt);
    else if (br == 2) slot = s_base[2] + s_woff[wid][2] + (int)__popcll(m2 & lt);
    ((int*)(ws + SLOT_OFF))[p] = slot;
    if (slot >= 0) ((int*)(ws + POS_OFF))[br * NPOS + slot] = p;
    out[OUT_MASK + p] = (et == 0) ? 1.0f : 0.0f;
}

// ---------------- K3: build bf16 input rows, 1 position per wave ------------
__device__ __forceinline__ float2 wmean(const float* __restrict__ wt,
                                        const int* __restrict__ wids, int lane) {
    float sx = 0.f, sy = 0.f;
    #pragma unroll
    for (int k = 0; k < 12; ++k) {
        const float* r = wt + (size_t)wids[k] * 128;
        float2 v = ld2(r + 2 * lane);
        sx += v.x; sy += v.y;
    }
    const float inv = 1.0f / 12.0f;
    return make_float2(sx * inv, sy * inv);
}

__global__ __launch_bounds__(256) void build_k(
    const float* __restrict__ ev_t,   const float* __restrict__ word_t,
    const float* __restrict__ sku_t,  const float* __restrict__ cat_t,
    const float* __restrict__ price_t,const float* __restrict__ url_t,
    const int* __restrict__ et_a,     const int* __restrict__ sku_id,
    const int* __restrict__ url_id,   const int* __restrict__ cat_id,
    const int* __restrict__ price_id, const int* __restrict__ word_id,
    float* __restrict__ out, char* ws)
{
    const int t = threadIdx.x, lane = t & 63, wid = t >> 6;
    const int p = blockIdx.x * 4 + wid;         // one position per wave
    const int et = et_a[p];
    if (et == 0) {  // pad: zero output row
        float4 z = {0.f, 0.f, 0.f, 0.f};
        float* orow = out + (size_t)p * 512;
        *reinterpret_cast<float4*>(&orow[lane * 8])     = z;
        *reinterpret_cast<float4*>(&orow[lane * 8 + 4]) = z;
        return;
    }
    const int slot = ((const int*)(ws + SLOT_OFF))[p];
    const float* evr = ev_t + et * 32;
    if (et <= 3) {  // sku: [ev 0..32)[sku 32..160)[cat 160..224)[price 224..256)[word 256..384)
        __hip_bfloat16* X = (__hip_bfloat16*)(ws + XS_OFF + (size_t)slot * 768);
        if (lane < 16) st2(X + 2 * lane, ld2(evr + 2 * lane));
        const float* sr = sku_t + (size_t)sku_id[p] * 128;
        st2(X + 32 + 2 * lane, ld2(sr + 2 * lane));
        const float* crr = cat_t + (size_t)cat_id[p] * 64;
        if (lane < 32) st2(X + 160 + 2 * lane, ld2(crr + 2 * lane));
        const float* prr = price_t + (size_t)price_id[p] * 32;
        if (lane < 16) st2(X + 224 + 2 * lane, ld2(prr + 2 * lane));
        float2 w = wmean(word_t, word_id + (size_t)p * 12, lane);
        st2(X + 256 + 2 * lane, w);
    } else if (et == 4) {  // url: [url 0..128)[ev 128..160)[pad 160..192)
        __hip_bfloat16* X = (__hip_bfloat16*)(ws + XU_OFF + (size_t)slot * 384);
        const float* ur = url_t + (size_t)url_id[p] * 128;
        st2(X + 2 * lane, ld2(ur + 2 * lane));
        if (lane < 16) st2(X + 128 + 2 * lane, ld2(evr + 2 * lane));
        if (lane < 16) st2(X + 160 + 2 * lane, make_float2(0.f, 0.f));
    } else {               // query: [ev 0..32)[word 32..160)[pad 160..192)
        __hip_bfloat16* X = (__hip_bfloat16*)(ws + XQ_OFF + (size_t)slot * 384);
        if (lane < 16) st2(X + 2 * lane, ld2(evr + 2 * lane));
        float2 w = wmean(word_t, word_id + (size_t)p * 12, lane);
        st2(X + 32 + 2 * lane, w);
        if (lane < 16) st2(X + 160 + 2 * lane, make_float2(0.f, 0.f));
    }
}

// ---------------- K4: merged branch GEMMs  out[pos]=relu(X*W^T+b) -----------
// 128x128 tile, BK=64, 4 waves (2x2) x 64x64, mfma_f32_16x16x32_bf16.
// T2 swizzle: linear LDS dest, source pre-swizzled, reads XOR'd (rule #21).
// Work-id layout: ny innermost + bijective XCD swizzle (m204) so the 4
// ny-blocks sharing an A-tile run adjacently on one XCD -> A re-reads hit L2.
__global__ __launch_bounds__(256, 2) void gemm_all_k(
    const char* __restrict__ ws_c, const float* __restrict__ sku_b,
    const float* __restrict__ url_b, const float* __restrict__ qry_b,
    float* __restrict__ out)
{
    const int z = blockIdx.z;
    const int count = ((const int*)(ws_c + CUR_OFF))[z];
    const int nmt = (count + 127) >> 7;
    const int nwg = nmt * 4;
    const int orig = blockIdx.x;
    if (orig >= nwg) return;
    // bijective XCD swizzle: dispatch round-robins orig%8 across XCDs; give
    // each XCD a contiguous chunk of work ids.
    const int q8 = nwg >> 3, r8 = nwg & 7;
    const int xcd = orig & 7, idx = orig >> 3;
    const int wg = (xcd < r8 ? xcd * (q8 + 1) : r8 * (q8 + 1) + (xcd - r8) * q8) + idx;
    const int mt = wg >> 2;             // ny innermost: 4 consecutive wg share mt
    const int row0 = mt * 128;
    const int nc0  = (wg & 3) * 128;

    const char* arena; const char* Wb; const float* bias; const int* posm;
    int astride, nkt;
    if (z == 0) { arena = ws_c + XS_OFF; Wb = ws_c + WSKU_OFF; bias = sku_b;
                  posm = (const int*)(ws_c + POS_OFF);          astride = 768; nkt = 6; }
    else if (z == 1) { arena = ws_c + XU_OFF; Wb = ws_c + WURL_OFF; bias = url_b;
                  posm = (const int*)(ws_c + POS_OFF) + NPOS;   astride = 384; nkt = 3; }
    else       { arena = ws_c + XQ_OFF; Wb = ws_c + WQRY_OFF; bias = qry_b;
                  posm = (const int*)(ws_c + POS_OFF) + 2*NPOS; astride = 384; nkt = 3; }
    const int wstride = astride;   // weight row bytes == X row bytes per branch

    __shared__ char lds[2][2][16384];   // [buf][A/B][128 rows x 128 B]

    const int t = threadIdx.x;
    const int lane = t & 63;
    const int wid  = t >> 6;
    const int wr = wid >> 1, wc = wid & 1;
    const int r = lane & 15, q = lane >> 4;

    auto stage = [&](int buf, int kt) {
        #pragma unroll
        for (int i = 0; i < 4; ++i) {
            int row = i * 32 + (t >> 3);
            int sb  = (t & 7) ^ (row & 7);
            const char* ga = arena + (size_t)(row0 + row) * astride + kt * 128 + sb * 16;
            __builtin_amdgcn_global_load_lds(AS1(ga), AS3(&lds[buf][0][i * 4096 + t * 16]), 16, 0, 0);
            const char* gb = Wb + (size_t)(nc0 + row) * wstride + kt * 128 + sb * 16;
            __builtin_amdgcn_global_load_lds(AS1(gb), AS3(&lds[buf][1][i * 4096 + t * 16]), 16, 0, 0);
        }
    };

    f32x4 acc[4][4];
    #pragma unroll
    for (int m = 0; m < 4; ++m)
        #pragma unroll
        for (int n = 0; n < 4; ++n)
            acc[m][n] = (f32x4){0.f, 0.f, 0.f, 0.f};

    stage(0, 0);
    __syncthreads();
    int cur = 0;
    for (int kt = 0; kt < nkt; ++kt) {
        if (kt + 1 < nkt) stage(cur ^ 1, kt + 1);
        #pragma unroll
        for (int kk = 0; kk < 2; ++kk) {
            bf16x8 af[4], bfr[4];
            #pragma unroll
            for (int m = 0; m < 4; ++m) {
                int arow = wr * 64 + m * 16 + r;
                af[m] = *reinterpret_cast<const bf16x8*>(
                    &lds[cur][0][arow * 128 + (((kk * 4 + q) ^ (r & 7)) * 16)]);
            }
            #pragma unroll
            for (int n = 0; n < 4; ++n) {
                int brow = wc * 64 + n * 16 + r;
                bfr[n] = *reinterpret_cast<const bf16x8*>(
                    &lds[cur][1][brow * 128 + (((kk * 4 + q) ^ (r & 7)) * 16)]);
            }
            #pragma unroll
            for (int m = 0; m < 4; ++m)
                #pragma unroll
                for (int n = 0; n < 4; ++n)
                    acc[m][n] = __builtin_amdgcn_mfma_f32_16x16x32_bf16(af[m], bfr[n], acc[m][n], 0, 0, 0);
        }
        __syncthreads();
        cur ^= 1;
    }

    float bv[4];
    #pragma unroll
    for (int n = 0; n < 4; ++n) bv[n] = bias[nc0 + wc * 64 + n * 16 + r];
    #pragma unroll
    for (int m = 0; m < 4; ++m) {
        #pragma unroll
        for (int j = 0; j < 4; ++j) {
            int rl = wr * 64 + m * 16 + q * 4 + j;
            int gr = row0 + rl;
            if (gr < count) {
                int pos = posm[gr];
                float* orow = out + (size_t)pos * 512 + nc0 + wc * 64;
                #pragma unroll
                for (int n = 0; n < 4; ++n)
                    orow[n * 16 + r] = fmaxf(acc[m][n][j] + bv[n], 0.f);
            }
        }
    }
}

// ---------------- host ----------------
extern "C" void kernel_launch(void* const* d_in, const int* in_sizes, int n_in,
                              void* d_out, int out_size, void* d_ws, size_t ws_size,
                              hipStream_t stream) {
    const float* ev_t    = (const float*)d_in[0];
    const float* word_t  = (const float*)d_in[1];
    const float* sku_t   = (const float*)d_in[2];
    const float* cat_t   = (const float*)d_in[3];
    const float* price_t = (const float*)d_in[4];
    const float* url_t   = (const float*)d_in[5];
    const float* sku_w   = (const float*)d_in[6];
    const float* sku_b   = (const float*)d_in[7];
    const float* url_w   = (const float*)d_in[8];
    const float* url_b   = (const float*)d_in[9];
    const float* query_w = (const float*)d_in[10];
    const float* query_b = (const float*)d_in[11];
    const int* event_type = (const int*)d_in[12];
    const int* sku_id     = (const int*)d_in[13];
    const int* url_id     = (const int*)d_in[14];
    const int* cat_id     = (const int*)d_in[15];
    const int* price_id   = (const int*)d_in[16];
    const int* word_id    = (const int*)d_in[17];

    char*  ws  = (char*)d_ws;
    float* out = (float*)d_out;

    wcvt_k<<<1536, 256, 0, stream>>>(sku_w, url_w, query_w, ws);
    alloc_k<<<256, 256, 0, stream>>>(event_type, out, ws);
    build_k<<<16384, 256, 0, stream>>>(ev_t, word_t, sku_t, cat_t, price_t, url_t,
                                       event_type, sku_id, url_id, cat_id, price_id,
                                       word_id, out, ws);
    dim3 gg(2048, 1, 3);
    gemm_all_k<<<gg, 256, 0, stream>>>(ws, sku_b, url_b, query_b, out);
}

// Round 5
// 101.906 us; speedup vs baseline: 1.8490x; 1.0168x over previous
//
#include <hip/hip_runtime.h>
#include <hip/hip_bf16.h>

// ---------------- workspace layout (bytes); ws_size ~1 GB ----------------
#define CUR_OFF   0          // int cur[3]  (atomic cursors == final counts)
#define SLOT_OFF  1024       // int slot_of_pos[65536]
#define POS_OFF   263168     // int posm[3][65536]
#define WSKU_OFF  1049600    // bf16 [512][384]
#define WURL_OFF  1442816    // bf16 [512][192] (cols 160..192 zero)
#define WQRY_OFF  1639424    // bf16 [512][192]
#define XS_OFF    1836032    // bf16 rows, stride 768 B, 65664 rows
#define XU_OFF    52265984   // bf16 rows, stride 384 B, 65664 rows
#define XQ_OFF    77480960   // bf16 rows, stride 384 B, 65664 rows

#define NPOS      65536
#define OUT_MASK  33554432   // 65536*512

typedef __attribute__((ext_vector_type(8))) short bf16x8;
typedef __attribute__((ext_vector_type(4))) float f32x4;

__device__ __forceinline__ unsigned short f2bf(float x) {
    unsigned int u = __float_as_uint(x);
    return (unsigned short)((u + 0x7fffu + ((u >> 16) & 1u)) >> 16);   // RNE
}
__device__ __forceinline__ void st2(__hip_bfloat16* d, float2 v) {
    unsigned int pk = (unsigned int)f2bf(v.x) | ((unsigned int)f2bf(v.y) << 16);
    *reinterpret_cast<unsigned int*>(d) = pk;
}
__device__ __forceinline__ float2 ld2(const float* p) {
    return *reinterpret_cast<const float2*>(p);
}

#define AS1(p) ((const __attribute__((address_space(1))) void*)(p))
#define AS3(p) ((__attribute__((address_space(3))) void*)(p))

// ---------------- K1: weight f32->bf16 + cursor zero ----------------
__global__ __launch_bounds__(256) void wcvt_k(const float* __restrict__ sw,
                                              const float* __restrict__ uw,
                                              const float* __restrict__ qw,
                                              char* ws) {
    int t = blockIdx.x * 256 + threadIdx.x;   // 393216 total
    if (t < 3) ((int*)(ws + CUR_OFF))[t] = 0;
    if (t < 196608) {
        ((unsigned short*)(ws + WSKU_OFF))[t] = f2bf(sw[t]);
    } else if (t < 294912) {
        int i = t - 196608; int n = i / 192, k = i % 192;
        ((unsigned short*)(ws + WURL_OFF))[i] = (k < 160) ? f2bf(uw[n * 160 + k]) : 0;
    } else if (t < 393216) {
        int i = t - 294912; int n = i / 192, k = i % 192;
        ((unsigned short*)(ws + WQRY_OFF))[i] = (k < 160) ? f2bf(qw[n * 160 + k]) : 0;
    }
}

// ---------------- K2: classify + slot allocation (block-aggregated) ----------
__global__ __launch_bounds__(256) void alloc_k(const int* __restrict__ et_a,
                                               float* __restrict__ out, char* ws) {
    __shared__ int s_wcnt[4][3];
    __shared__ int s_base[3];
    __shared__ int s_woff[4][3];
    const int t = threadIdx.x, lane = t & 63, wid = t >> 6;
    int p = blockIdx.x * 256 + t;
    int et = et_a[p];
    int br = (et >= 1 && et <= 3) ? 0 : (et == 4 ? 1 : (et == 5 ? 2 : -1));
    unsigned long long m0 = __ballot(br == 0);
    unsigned long long m1 = __ballot(br == 1);
    unsigned long long m2 = __ballot(br == 2);
    if (lane == 0) {
        s_wcnt[wid][0] = (int)__popcll(m0);
        s_wcnt[wid][1] = (int)__popcll(m1);
        s_wcnt[wid][2] = (int)__popcll(m2);
    }
    __syncthreads();
    if (t < 3) {
        int c0 = s_wcnt[0][t], c1 = s_wcnt[1][t], c2 = s_wcnt[2][t], c3 = s_wcnt[3][t];
        int tot = c0 + c1 + c2 + c3;
        s_base[t] = tot ? atomicAdd(&((int*)(ws + CUR_OFF))[t], tot) : 0;
        s_woff[0][t] = 0; s_woff[1][t] = c0; s_woff[2][t] = c0 + c1; s_woff[3][t] = c0 + c1 + c2;
    }
    __syncthreads();
    unsigned long long lt = (1ull << lane) - 1ull;
    int slot = -1;
    if (br == 0)      slot = s_base[0] + s_woff[wid][0] + (int)__popcll(m0 & lt);
    else if (br == 1) slot = s_base[1] + s_woff[wid][1] + (int)__popcll(m1 & lt);
    else if (br == 2) slot = s_base[2] + s_woff[wid][2] + (int)__popcll(m2 & lt);
    ((int*)(ws + SLOT_OFF))[p] = slot;
    if (slot >= 0) ((int*)(ws + POS_OFF))[br * NPOS + slot] = p;
    __builtin_nontemporal_store((et == 0) ? 1.0f : 0.0f, &out[OUT_MASK + p]);
}

// ---------------- K3: build bf16 input rows, 1 position per wave ------------
__device__ __forceinline__ float2 wmean(const float* __restrict__ wt,
                                        const int* __restrict__ wids, int lane) {
    float sx = 0.f, sy = 0.f;
    #pragma unroll
    for (int k = 0; k < 12; ++k) {
        const float* r = wt + (size_t)wids[k] * 128;
        float2 v = ld2(r + 2 * lane);
        sx += v.x; sy += v.y;
    }
    const float inv = 1.0f / 12.0f;
    return make_float2(sx * inv, sy * inv);
}

__global__ __launch_bounds__(256) void build_k(
    const float* __restrict__ ev_t,   const float* __restrict__ word_t,
    const float* __restrict__ sku_t,  const float* __restrict__ cat_t,
    const float* __restrict__ price_t,const float* __restrict__ url_t,
    const int* __restrict__ et_a,     const int* __restrict__ sku_id,
    const int* __restrict__ url_id,   const int* __restrict__ cat_id,
    const int* __restrict__ price_id, const int* __restrict__ word_id,
    float* __restrict__ out, char* ws)
{
    const int t = threadIdx.x, lane = t & 63, wid = t >> 6;
    const int p = blockIdx.x * 4 + wid;         // one position per wave
    const int et = et_a[p];
    if (et == 0) {  // pad: zero output row (nontemporal: out is write-once)
        f32x4 z = {0.f, 0.f, 0.f, 0.f};
        float* orow = out + (size_t)p * 512;
        __builtin_nontemporal_store(z, reinterpret_cast<f32x4*>(&orow[lane * 8]));
        __builtin_nontemporal_store(z, reinterpret_cast<f32x4*>(&orow[lane * 8 + 4]));
        return;
    }
    const int slot = ((const int*)(ws + SLOT_OFF))[p];
    const float* evr = ev_t + et * 32;
    if (et <= 3) {  // sku: [ev 0..32)[sku 32..160)[cat 160..224)[price 224..256)[word 256..384)
        __hip_bfloat16* X = (__hip_bfloat16*)(ws + XS_OFF + (size_t)slot * 768);
        if (lane < 16) st2(X + 2 * lane, ld2(evr + 2 * lane));
        const float* sr = sku_t + (size_t)sku_id[p] * 128;
        st2(X + 32 + 2 * lane, ld2(sr + 2 * lane));
        const float* crr = cat_t + (size_t)cat_id[p] * 64;
        if (lane < 32) st2(X + 160 + 2 * lane, ld2(crr + 2 * lane));
        const float* prr = price_t + (size_t)price_id[p] * 32;
        if (lane < 16) st2(X + 224 + 2 * lane, ld2(prr + 2 * lane));
        float2 w = wmean(word_t, word_id + (size_t)p * 12, lane);
        st2(X + 256 + 2 * lane, w);
    } else if (et == 4) {  // url: [url 0..128)[ev 128..160)[pad 160..192)
        __hip_bfloat16* X = (__hip_bfloat16*)(ws + XU_OFF + (size_t)slot * 384);
        const float* ur = url_t + (size_t)url_id[p] * 128;
        st2(X + 2 * lane, ld2(ur + 2 * lane));
        if (lane < 16) st2(X + 128 + 2 * lane, ld2(evr + 2 * lane));
        if (lane < 16) st2(X + 160 + 2 * lane, make_float2(0.f, 0.f));
    } else {               // query: [ev 0..32)[word 32..160)[pad 160..192)
        __hip_bfloat16* X = (__hip_bfloat16*)(ws + XQ_OFF + (size_t)slot * 384);
        if (lane < 16) st2(X + 2 * lane, ld2(evr + 2 * lane));
        float2 w = wmean(word_t, word_id + (size_t)p * 12, lane);
        st2(X + 32 + 2 * lane, w);
        if (lane < 16) st2(X + 160 + 2 * lane, make_float2(0.f, 0.f));
    }
}

// ---------------- K4: merged branch GEMMs  out[pos]=relu(X*W^T+b) -----------
// 128x128 tile, BK=64, 4 waves (2x2) x 64x64, mfma_f32_16x16x32_bf16.
// T2 swizzle: linear LDS dest, source pre-swizzled, reads XOR'd (rule #21).
// ny innermost + bijective XCD swizzle (m204); out stores nontemporal to keep
// word-table / X-arena L3-resident across replays.
__global__ __launch_bounds__(256, 2) void gemm_all_k(
    const char* __restrict__ ws_c, const float* __restrict__ sku_b,
    const float* __restrict__ url_b, const float* __restrict__ qry_b,
    float* __restrict__ out)
{
    const int z = blockIdx.z;
    const int count = ((const int*)(ws_c + CUR_OFF))[z];
    const int nmt = (count + 127) >> 7;
    const int nwg = nmt * 4;
    const int orig = blockIdx.x;
    if (orig >= nwg) return;
    const int q8 = nwg >> 3, r8 = nwg & 7;
    const int xcd = orig & 7, idx = orig >> 3;
    const int wg = (xcd < r8 ? xcd * (q8 + 1) : r8 * (q8 + 1) + (xcd - r8) * q8) + idx;
    const int mt = wg >> 2;             // ny innermost: 4 consecutive wg share mt
    const int row0 = mt * 128;
    const int nc0  = (wg & 3) * 128;

    const char* arena; const char* Wb; const float* bias; const int* posm;
    int astride, nkt;
    if (z == 0) { arena = ws_c + XS_OFF; Wb = ws_c + WSKU_OFF; bias = sku_b;
                  posm = (const int*)(ws_c + POS_OFF);          astride = 768; nkt = 6; }
    else if (z == 1) { arena = ws_c + XU_OFF; Wb = ws_c + WURL_OFF; bias = url_b;
                  posm = (const int*)(ws_c + POS_OFF) + NPOS;   astride = 384; nkt = 3; }
    else       { arena = ws_c + XQ_OFF; Wb = ws_c + WQRY_OFF; bias = qry_b;
                  posm = (const int*)(ws_c + POS_OFF) + 2*NPOS; astride = 384; nkt = 3; }
    const int wstride = astride;

    __shared__ char lds[2][2][16384];   // [buf][A/B][128 rows x 128 B]

    const int t = threadIdx.x;
    const int lane = t & 63;
    const int wid  = t >> 6;
    const int wr = wid >> 1, wc = wid & 1;
    const int r = lane & 15, q = lane >> 4;

    auto stage = [&](int buf, int kt) {
        #pragma unroll
        for (int i = 0; i < 4; ++i) {
            int row = i * 32 + (t >> 3);
            int sb  = (t & 7) ^ (row & 7);
            const char* ga = arena + (size_t)(row0 + row) * astride + kt * 128 + sb * 16;
            __builtin_amdgcn_global_load_lds(AS1(ga), AS3(&lds[buf][0][i * 4096 + t * 16]), 16, 0, 0);
            const char* gb = Wb + (size_t)(nc0 + row) * wstride + kt * 128 + sb * 16;
            __builtin_amdgcn_global_load_lds(AS1(gb), AS3(&lds[buf][1][i * 4096 + t * 16]), 16, 0, 0);
        }
    };

    f32x4 acc[4][4];
    #pragma unroll
    for (int m = 0; m < 4; ++m)
        #pragma unroll
        for (int n = 0; n < 4; ++n)
            acc[m][n] = (f32x4){0.f, 0.f, 0.f, 0.f};

    stage(0, 0);
    __syncthreads();
    int cur = 0;
    for (int kt = 0; kt < nkt; ++kt) {
        if (kt + 1 < nkt) stage(cur ^ 1, kt + 1);
        #pragma unroll
        for (int kk = 0; kk < 2; ++kk) {
            bf16x8 af[4], bfr[4];
            #pragma unroll
            for (int m = 0; m < 4; ++m) {
                int arow = wr * 64 + m * 16 + r;
                af[m] = *reinterpret_cast<const bf16x8*>(
                    &lds[cur][0][arow * 128 + (((kk * 4 + q) ^ (r & 7)) * 16)]);
            }
            #pragma unroll
            for (int n = 0; n < 4; ++n) {
                int brow = wc * 64 + n * 16 + r;
                bfr[n] = *reinterpret_cast<const bf16x8*>(
                    &lds[cur][1][brow * 128 + (((kk * 4 + q) ^ (r & 7)) * 16)]);
            }
            #pragma unroll
            for (int m = 0; m < 4; ++m)
                #pragma unroll
                for (int n = 0; n < 4; ++n)
                    acc[m][n] = __builtin_amdgcn_mfma_f32_16x16x32_bf16(af[m], bfr[n], acc[m][n], 0, 0, 0);
        }
        __syncthreads();
        cur ^= 1;
    }

    float bv[4];
    #pragma unroll
    for (int n = 0; n < 4; ++n) bv[n] = bias[nc0 + wc * 64 + n * 16 + r];
    #pragma unroll
    for (int m = 0; m < 4; ++m) {
        #pragma unroll
        for (int j = 0; j < 4; ++j) {
            int rl = wr * 64 + m * 16 + q * 4 + j;
            int gr = row0 + rl;
            if (gr < count) {
                int pos = posm[gr];
                float* orow = out + (size_t)pos * 512 + nc0 + wc * 64;
                #pragma unroll
                for (int n = 0; n < 4; ++n)
                    __builtin_nontemporal_store(fmaxf(acc[m][n][j] + bv[n], 0.f),
                                                &orow[n * 16 + r]);
            }
        }
    }
}

// ---------------- host ----------------
extern "C" void kernel_launch(void* const* d_in, const int* in_sizes, int n_in,
                              void* d_out, int out_size, void* d_ws, size_t ws_size,
                              hipStream_t stream) {
    const float* ev_t    = (const float*)d_in[0];
    const float* word_t  = (const float*)d_in[1];
    const float* sku_t   = (const float*)d_in[2];
    const float* cat_t   = (const float*)d_in[3];
    const float* price_t = (const float*)d_in[4];
    const float* url_t   = (const float*)d_in[5];
    const float* sku_w   = (const float*)d_in[6];
    const float* sku_b   = (const float*)d_in[7];
    const float* url_w   = (const float*)d_in[8];
    const float* url_b   = (const float*)d_in[9];
    const float* query_w = (const float*)d_in[10];
    const float* query_b = (const float*)d_in[11];
    const int* event_type = (const int*)d_in[12];
    const int* sku_id     = (const int*)d_in[13];
    const int* url_id     = (const int*)d_in[14];
    const int* cat_id     = (const int*)d_in[15];
    const int* price_id   = (const int*)d_in[16];
    const int* word_id    = (const int*)d_in[17];

    char*  ws  = (char*)d_ws;
    float* out = (float*)d_out;

    wcvt_k<<<1536, 256, 0, stream>>>(sku_w, url_w, query_w, ws);
    alloc_k<<<256, 256, 0, stream>>>(event_type, out, ws);
    build_k<<<16384, 256, 0, stream>>>(ev_t, word_t, sku_t, cat_t, price_t, url_t,
                                       event_type, sku_id, url_id, cat_id, price_id,
                                       word_id, out, ws);
    dim3 gg(2048, 1, 3);
    gemm_all_k<<<gg, 256, 0, stream>>>(ws, sku_b, url_b, query_b, out);
}

// Round 6
// 97.625 us; speedup vs baseline: 1.9301x; 1.0439x over previous
//
#include <hip/hip_runtime.h>
#include <hip/hip_bf16.h>

// ---------------- workspace layout (bytes); ws_size ~1 GB ----------------
#define CUR_OFF   0          // int cur[3]  (atomic cursors == final counts)
#define SLOT_OFF  1024       // int slot_of_pos[65536]
#define POS_OFF   263168     // int posm[3][65536]
#define WSKU_OFF  1049600    // bf16 [512][384]
#define WURL_OFF  1442816    // bf16 [512][192] (cols 160..192 zero)
#define WQRY_OFF  1639424    // bf16 [512][192]
#define WBF_OFF   2097152    // bf16 word table [100000][128] = 25.6 MB
#define XS_OFF    27697152   // bf16 rows, stride 768 B, 65664 rows
#define XU_OFF    78127104   // bf16 rows, stride 384 B, 65664 rows
#define XQ_OFF    103342080  // bf16 rows, stride 384 B, 65664 rows  (end ~122.6 MB)

#define NPOS      65536
#define OUT_MASK  33554432   // 65536*512

typedef __attribute__((ext_vector_type(8))) short bf16x8;
typedef __attribute__((ext_vector_type(4))) float f32x4;
typedef __attribute__((ext_vector_type(4))) unsigned int u32x4;

__device__ __forceinline__ unsigned short f2bf(float x) {
    unsigned int u = __float_as_uint(x);
    return (unsigned short)((u + 0x7fffu + ((u >> 16) & 1u)) >> 16);   // RNE
}
__device__ __forceinline__ void st2(__hip_bfloat16* d, float2 v) {
    unsigned int pk = (unsigned int)f2bf(v.x) | ((unsigned int)f2bf(v.y) << 16);
    *reinterpret_cast<unsigned int*>(d) = pk;
}
__device__ __forceinline__ float2 ld2(const float* p) {
    return *reinterpret_cast<const float2*>(p);
}

#define AS1(p) ((const __attribute__((address_space(1))) void*)(p))
#define AS3(p) ((__attribute__((address_space(3))) void*)(p))

// ---- K1: word table f32->bf16 + weight f32->bf16 + cursor zero -------------
// blocks [0,6250): word table (12.8M elems, 8/thread)
// blocks [6250,7786): weights (393216 elems) + cursor zero
__global__ __launch_bounds__(256) void prep_k(const float* __restrict__ sw,
                                              const float* __restrict__ uw,
                                              const float* __restrict__ qw,
                                              const float* __restrict__ word_t,
                                              char* ws) {
    const int b = blockIdx.x, t = threadIdx.x;
    if (b < 6250) {
        size_t i = ((size_t)b * 256 + t) * 8;          // 6250*256*8 = 12.8M exactly
        f32x4 v0 = *reinterpret_cast<const f32x4*>(word_t + i);
        f32x4 v1 = *reinterpret_cast<const f32x4*>(word_t + i + 4);
        u32x4 pk;
        pk.x = (unsigned int)f2bf(v0.x) | ((unsigned int)f2bf(v0.y) << 16);
        pk.y = (unsigned int)f2bf(v0.z) | ((unsigned int)f2bf(v0.w) << 16);
        pk.z = (unsigned int)f2bf(v1.x) | ((unsigned int)f2bf(v1.y) << 16);
        pk.w = (unsigned int)f2bf(v1.z) | ((unsigned int)f2bf(v1.w) << 16);
        *reinterpret_cast<u32x4*>((unsigned short*)(ws + WBF_OFF) + i) = pk;
        return;
    }
    int tt = (b - 6250) * 256 + t;   // 393216 total
    if (tt < 3) ((int*)(ws + CUR_OFF))[tt] = 0;
    if (tt < 196608) {
        ((unsigned short*)(ws + WSKU_OFF))[tt] = f2bf(sw[tt]);
    } else if (tt < 294912) {
        int i = tt - 196608; int n = i / 192, k = i % 192;
        ((unsigned short*)(ws + WURL_OFF))[i] = (k < 160) ? f2bf(uw[n * 160 + k]) : 0;
    } else {
        int i = tt - 294912; int n = i / 192, k = i % 192;
        ((unsigned short*)(ws + WQRY_OFF))[i] = (k < 160) ? f2bf(qw[n * 160 + k]) : 0;
    }
}

// ---------------- K2: classify + slot allocation (block-aggregated) ----------
__global__ __launch_bounds__(256) void alloc_k(const int* __restrict__ et_a,
                                               float* __restrict__ out, char* ws) {
    __shared__ int s_wcnt[4][3];
    __shared__ int s_base[3];
    __shared__ int s_woff[4][3];
    const int t = threadIdx.x, lane = t & 63, wid = t >> 6;
    int p = blockIdx.x * 256 + t;
    int et = et_a[p];
    int br = (et >= 1 && et <= 3) ? 0 : (et == 4 ? 1 : (et == 5 ? 2 : -1));
    unsigned long long m0 = __ballot(br == 0);
    unsigned long long m1 = __ballot(br == 1);
    unsigned long long m2 = __ballot(br == 2);
    if (lane == 0) {
        s_wcnt[wid][0] = (int)__popcll(m0);
        s_wcnt[wid][1] = (int)__popcll(m1);
        s_wcnt[wid][2] = (int)__popcll(m2);
    }
    __syncthreads();
    if (t < 3) {
        int c0 = s_wcnt[0][t], c1 = s_wcnt[1][t], c2 = s_wcnt[2][t], c3 = s_wcnt[3][t];
        int tot = c0 + c1 + c2 + c3;
        s_base[t] = tot ? atomicAdd(&((int*)(ws + CUR_OFF))[t], tot) : 0;
        s_woff[0][t] = 0; s_woff[1][t] = c0; s_woff[2][t] = c0 + c1; s_woff[3][t] = c0 + c1 + c2;
    }
    __syncthreads();
    unsigned long long lt = (1ull << lane) - 1ull;
    int slot = -1;
    if (br == 0)      slot = s_base[0] + s_woff[wid][0] + (int)__popcll(m0 & lt);
    else if (br == 1) slot = s_base[1] + s_woff[wid][1] + (int)__popcll(m1 & lt);
    else if (br == 2) slot = s_base[2] + s_woff[wid][2] + (int)__popcll(m2 & lt);
    ((int*)(ws + SLOT_OFF))[p] = slot;
    if (slot >= 0) ((int*)(ws + POS_OFF))[br * NPOS + slot] = p;
    __builtin_nontemporal_store((et == 0) ? 1.0f : 0.0f, &out[OUT_MASK + p]);
}

// ---------------- K3: build bf16 input rows, 1 position per wave ------------
__device__ __forceinline__ float2 wmean_bf(const unsigned short* __restrict__ wt,
                                           const int* __restrict__ wids, int lane) {
    float sx = 0.f, sy = 0.f;
    #pragma unroll
    for (int k = 0; k < 12; ++k) {
        unsigned int u = *reinterpret_cast<const unsigned int*>(
            wt + (size_t)wids[k] * 128 + 2 * lane);
        sx += __uint_as_float(u << 16);
        sy += __uint_as_float(u & 0xffff0000u);
    }
    const float inv = 1.0f / 12.0f;
    return make_float2(sx * inv, sy * inv);
}

__global__ __launch_bounds__(256) void build_k(
    const float* __restrict__ ev_t,
    const float* __restrict__ sku_t,  const float* __restrict__ cat_t,
    const float* __restrict__ price_t,const float* __restrict__ url_t,
    const int* __restrict__ et_a,     const int* __restrict__ sku_id,
    const int* __restrict__ url_id,   const int* __restrict__ cat_id,
    const int* __restrict__ price_id, const int* __restrict__ word_id,
    float* __restrict__ out, char* ws)
{
    const int t = threadIdx.x, lane = t & 63, wid = t >> 6;
    const int p = blockIdx.x * 4 + wid;         // one position per wave
    const int et = et_a[p];
    if (et == 0) {  // pad: zero output row (nontemporal: out is write-once)
        f32x4 z = {0.f, 0.f, 0.f, 0.f};
        float* orow = out + (size_t)p * 512;
        __builtin_nontemporal_store(z, reinterpret_cast<f32x4*>(&orow[lane * 8]));
        __builtin_nontemporal_store(z, reinterpret_cast<f32x4*>(&orow[lane * 8 + 4]));
        return;
    }
    const int slot = ((const int*)(ws + SLOT_OFF))[p];
    const unsigned short* wbf = (const unsigned short*)(ws + WBF_OFF);
    const float* evr = ev_t + et * 32;
    if (et <= 3) {  // sku: [ev 0..32)[sku 32..160)[cat 160..224)[price 224..256)[word 256..384)
        __hip_bfloat16* X = (__hip_bfloat16*)(ws + XS_OFF + (size_t)slot * 768);
        if (lane < 16) st2(X + 2 * lane, ld2(evr + 2 * lane));
        const float* sr = sku_t + (size_t)sku_id[p] * 128;
        st2(X + 32 + 2 * lane, ld2(sr + 2 * lane));
        const float* crr = cat_t + (size_t)cat_id[p] * 64;
        if (lane < 32) st2(X + 160 + 2 * lane, ld2(crr + 2 * lane));
        const float* prr = price_t + (size_t)price_id[p] * 32;
        if (lane < 16) st2(X + 224 + 2 * lane, ld2(prr + 2 * lane));
        float2 w = wmean_bf(wbf, word_id + (size_t)p * 12, lane);
        st2(X + 256 + 2 * lane, w);
    } else if (et == 4) {  // url: [url 0..128)[ev 128..160)[pad 160..192)
        __hip_bfloat16* X = (__hip_bfloat16*)(ws + XU_OFF + (size_t)slot * 384);
        const float* ur = url_t + (size_t)url_id[p] * 128;
        st2(X + 2 * lane, ld2(ur + 2 * lane));
        if (lane < 16) st2(X + 128 + 2 * lane, ld2(evr + 2 * lane));
        if (lane < 16) st2(X + 160 + 2 * lane, make_float2(0.f, 0.f));
    } else {               // query: [ev 0..32)[word 32..160)[pad 160..192)
        __hip_bfloat16* X = (__hip_bfloat16*)(ws + XQ_OFF + (size_t)slot * 384);
        if (lane < 16) st2(X + 2 * lane, ld2(evr + 2 * lane));
        float2 w = wmean_bf(wbf, word_id + (size_t)p * 12, lane);
        st2(X + 32 + 2 * lane, w);
        if (lane < 16) st2(X + 160 + 2 * lane, make_float2(0.f, 0.f));
    }
}

// ---------------- K4: merged branch GEMMs  out[pos]=relu(X*W^T+b) -----------
// 128x128 tile, BK=64, 4 waves (2x2) x 64x64, mfma_f32_16x16x32_bf16.
// T2 swizzle: linear LDS dest, source pre-swizzled, reads XOR'd (rule #21).
// ny innermost + bijective XCD swizzle (m204); out stores nontemporal.
__global__ __launch_bounds__(256, 2) void gemm_all_k(
    const char* __restrict__ ws_c, const float* __restrict__ sku_b,
    const float* __restrict__ url_b, const float* __restrict__ qry_b,
    float* __restrict__ out)
{
    const int z = blockIdx.z;
    const int count = ((const int*)(ws_c + CUR_OFF))[z];
    const int nmt = (count + 127) >> 7;
    const int nwg = nmt * 4;
    const int orig = blockIdx.x;
    if (orig >= nwg) return;
    const int q8 = nwg >> 3, r8 = nwg & 7;
    const int xcd = orig & 7, idx = orig >> 3;
    const int wg = (xcd < r8 ? xcd * (q8 + 1) : r8 * (q8 + 1) + (xcd - r8) * q8) + idx;
    const int mt = wg >> 2;             // ny innermost: 4 consecutive wg share mt
    const int row0 = mt * 128;
    const int nc0  = (wg & 3) * 128;

    const char* arena; const char* Wb; const float* bias; const int* posm;
    int astride, nkt;
    if (z == 0) { arena = ws_c + XS_OFF; Wb = ws_c + WSKU_OFF; bias = sku_b;
                  posm = (const int*)(ws_c + POS_OFF);          astride = 768; nkt = 6; }
    else if (z == 1) { arena = ws_c + XU_OFF; Wb = ws_c + WURL_OFF; bias = url_b;
                  posm = (const int*)(ws_c + POS_OFF) + NPOS;   astride = 384; nkt = 3; }
    else       { arena = ws_c + XQ_OFF; Wb = ws_c + WQRY_OFF; bias = qry_b;
                  posm = (const int*)(ws_c + POS_OFF) + 2*NPOS; astride = 384; nkt = 3; }
    const int wstride = astride;

    __shared__ char lds[2][2][16384];   // [buf][A/B][128 rows x 128 B]

    const int t = threadIdx.x;
    const int lane = t & 63;
    const int wid  = t >> 6;
    const int wr = wid >> 1, wc = wid & 1;
    const int r = lane & 15, q = lane >> 4;

    auto stage = [&](int buf, int kt) {
        #pragma unroll
        for (int i = 0; i < 4; ++i) {
            int row = i * 32 + (t >> 3);
            int sb  = (t & 7) ^ (row & 7);
            const char* ga = arena + (size_t)(row0 + row) * astride + kt * 128 + sb * 16;
            __builtin_amdgcn_global_load_lds(AS1(ga), AS3(&lds[buf][0][i * 4096 + t * 16]), 16, 0, 0);
            const char* gb = Wb + (size_t)(nc0 + row) * wstride + kt * 128 + sb * 16;
            __builtin_amdgcn_global_load_lds(AS1(gb), AS3(&lds[buf][1][i * 4096 + t * 16]), 16, 0, 0);
        }
    };

    f32x4 acc[4][4];
    #pragma unroll
    for (int m = 0; m < 4; ++m)
        #pragma unroll
        for (int n = 0; n < 4; ++n)
            acc[m][n] = (f32x4){0.f, 0.f, 0.f, 0.f};

    stage(0, 0);
    __syncthreads();
    int cur = 0;
    for (int kt = 0; kt < nkt; ++kt) {
        if (kt + 1 < nkt) stage(cur ^ 1, kt + 1);
        #pragma unroll
        for (int kk = 0; kk < 2; ++kk) {
            bf16x8 af[4], bfr[4];
            #pragma unroll
            for (int m = 0; m < 4; ++m) {
                int arow = wr * 64 + m * 16 + r;
                af[m] = *reinterpret_cast<const bf16x8*>(
                    &lds[cur][0][arow * 128 + (((kk * 4 + q) ^ (r & 7)) * 16)]);
            }
            #pragma unroll
            for (int n = 0; n < 4; ++n) {
                int brow = wc * 64 + n * 16 + r;
                bfr[n] = *reinterpret_cast<const bf16x8*>(
                    &lds[cur][1][brow * 128 + (((kk * 4 + q) ^ (r & 7)) * 16)]);
            }
            #pragma unroll
            for (int m = 0; m < 4; ++m)
                #pragma unroll
                for (int n = 0; n < 4; ++n)
                    acc[m][n] = __builtin_amdgcn_mfma_f32_16x16x32_bf16(af[m], bfr[n], acc[m][n], 0, 0, 0);
        }
        __syncthreads();
        cur ^= 1;
    }

    float bv[4];
    #pragma unroll
    for (int n = 0; n < 4; ++n) bv[n] = bias[nc0 + wc * 64 + n * 16 + r];
    #pragma unroll
    for (int m = 0; m < 4; ++m) {
        #pragma unroll
        for (int j = 0; j < 4; ++j) {
            int rl = wr * 64 + m * 16 + q * 4 + j;
            int gr = row0 + rl;
            if (gr < count) {
                int pos = posm[gr];
                float* orow = out + (size_t)pos * 512 + nc0 + wc * 64;
                #pragma unroll
                for (int n = 0; n < 4; ++n)
                    __builtin_nontemporal_store(fmaxf(acc[m][n][j] + bv[n], 0.f),
                                                &orow[n * 16 + r]);
            }
        }
    }
}

// ---------------- host ----------------
extern "C" void kernel_launch(void* const* d_in, const int* in_sizes, int n_in,
                              void* d_out, int out_size, void* d_ws, size_t ws_size,
                              hipStream_t stream) {
    const float* ev_t    = (const float*)d_in[0];
    const float* word_t  = (const float*)d_in[1];
    const float* sku_t   = (const float*)d_in[2];
    const float* cat_t   = (const float*)d_in[3];
    const float* price_t = (const float*)d_in[4];
    const float* url_t   = (const float*)d_in[5];
    const float* sku_w   = (const float*)d_in[6];
    const float* sku_b   = (const float*)d_in[7];
    const float* url_w   = (const float*)d_in[8];
    const float* url_b   = (const float*)d_in[9];
    const float* query_w = (const float*)d_in[10];
    const float* query_b = (const float*)d_in[11];
    const int* event_type = (const int*)d_in[12];
    const int* sku_id     = (const int*)d_in[13];
    const int* url_id     = (const int*)d_in[14];
    const int* cat_id     = (const int*)d_in[15];
    const int* price_id   = (const int*)d_in[16];
    const int* word_id    = (const int*)d_in[17];

    char*  ws  = (char*)d_ws;
    float* out = (float*)d_out;

    prep_k<<<7786, 256, 0, stream>>>(sku_w, url_w, query_w, word_t, ws);
    alloc_k<<<256, 256, 0, stream>>>(event_type, out, ws);
    build_k<<<16384, 256, 0, stream>>>(ev_t, sku_t, cat_t, price_t, url_t,
                                       event_type, sku_id, url_id, cat_id, price_id,
                                       word_id, out, ws);
    dim3 gg(2048, 1, 3);
    gemm_all_k<<<gg, 256, 0, stream>>>(ws, sku_b, url_b, query_b, out);
}

// Round 7
// 92.791 us; speedup vs baseline: 2.0307x; 1.0521x over previous
//
#include <hip/hip_runtime.h>
#include <hip/hip_bf16.h>
#if !__has_builtin(__builtin_amdgcn_cvt_pk_fp8_f32) || !__has_builtin(__builtin_amdgcn_cvt_pk_f32_fp8)
#include <hip/hip_fp8.h>
#endif

// ---------------- workspace layout (bytes); ws_size ~1 GB ----------------
#define CUR_OFF   0          // int cur[3]  (atomic cursors == final counts)
#define SLOT_OFF  1024       // int slot_of_pos[65536]
#define POS_OFF   263168     // int posm[3][65536]
#define WSKU_OFF  1049600    // bf16 [512][384]
#define WURL_OFF  1442816    // bf16 [512][192] (cols 160..192 zero)
#define WQRY_OFF  1639424    // bf16 [512][192]
#define WF8_OFF   2097152    // fp8-e4m3 word table [100000][128] = 12.8 MB (values x64)
#define XS_OFF    27697152   // bf16 rows, stride 768 B, 65664 rows
#define XU_OFF    78127104   // bf16 rows, stride 384 B, 65664 rows
#define XQ_OFF    103342080  // bf16 rows, stride 384 B, 65664 rows  (end ~122.6 MB)

#define NPOS      65536
#define OUT_MASK  33554432   // 65536*512
#define F8_SCALE  64.0f
#define F8_INV    (1.0f / (12.0f * 64.0f))

typedef __attribute__((ext_vector_type(8))) short bf16x8;
typedef __attribute__((ext_vector_type(4))) float f32x4;
typedef __attribute__((ext_vector_type(2))) float f32x2;
typedef __attribute__((ext_vector_type(2))) unsigned int u32x2;

__device__ __forceinline__ unsigned short f2bf(float x) {
    unsigned int u = __float_as_uint(x);
    return (unsigned short)((u + 0x7fffu + ((u >> 16) & 1u)) >> 16);   // RNE
}
__device__ __forceinline__ void st2(__hip_bfloat16* d, float2 v) {
    unsigned int pk = (unsigned int)f2bf(v.x) | ((unsigned int)f2bf(v.y) << 16);
    *reinterpret_cast<unsigned int*>(d) = pk;
}
__device__ __forceinline__ float2 ld2(const float* p) {
    return *reinterpret_cast<const float2*>(p);
}

// packed fp8 e4m3 encode: 4 floats -> u32
__device__ __forceinline__ unsigned int pk4_fp8(float a, float b, float c, float d) {
#if __has_builtin(__builtin_amdgcn_cvt_pk_fp8_f32)
    unsigned int v = 0;
    v = __builtin_amdgcn_cvt_pk_fp8_f32(a, b, v, false);
    v = __builtin_amdgcn_cvt_pk_fp8_f32(c, d, v, true);
    return v;
#else
    __hip_fp8_e4m3 fa(a), fb(b), fc(c), fd(d);
    return (unsigned int)fa.__x | ((unsigned int)fb.__x << 8)
         | ((unsigned int)fc.__x << 16) | ((unsigned int)fd.__x << 24);
#endif
}
// packed fp8 e4m3 decode: low 2 bytes of u -> 2 floats
__device__ __forceinline__ float2 upk2_fp8(unsigned int u) {
#if __has_builtin(__builtin_amdgcn_cvt_pk_f32_fp8)
    f32x2 r = __builtin_amdgcn_cvt_pk_f32_fp8(u, false);
    return make_float2(r.x, r.y);
#else
    __hip_fp8_e4m3 fa, fb;
    fa.__x = (unsigned char)(u & 0xff);
    fb.__x = (unsigned char)((u >> 8) & 0xff);
    return make_float2((float)fa, (float)fb);
#endif
}

#define AS1(p) ((const __attribute__((address_space(1))) void*)(p))
#define AS3(p) ((__attribute__((address_space(3))) void*)(p))

// ---- K1: word table f32->fp8(x64) + weight f32->bf16 + cursor zero ---------
// blocks [0,6250): word table (12.8M elems, 8/thread)
// blocks [6250,7786): weights (393216 elems) + cursor zero
__global__ __launch_bounds__(256) void prep_k(const float* __restrict__ sw,
                                              const float* __restrict__ uw,
                                              const float* __restrict__ qw,
                                              const float* __restrict__ word_t,
                                              char* ws) {
    const int b = blockIdx.x, t = threadIdx.x;
    if (b < 6250) {
        size_t i = ((size_t)b * 256 + t) * 8;          // 6250*256*8 = 12.8M exactly
        f32x4 v0 = *reinterpret_cast<const f32x4*>(word_t + i);
        f32x4 v1 = *reinterpret_cast<const f32x4*>(word_t + i + 4);
        u32x2 pk;
        pk.x = pk4_fp8(v0.x * F8_SCALE, v0.y * F8_SCALE, v0.z * F8_SCALE, v0.w * F8_SCALE);
        pk.y = pk4_fp8(v1.x * F8_SCALE, v1.y * F8_SCALE, v1.z * F8_SCALE, v1.w * F8_SCALE);
        *reinterpret_cast<u32x2*>((unsigned char*)(ws + WF8_OFF) + i) = pk;
        return;
    }
    int tt = (b - 6250) * 256 + t;   // 393216 total
    if (tt < 3) ((int*)(ws + CUR_OFF))[tt] = 0;
    if (tt < 196608) {
        ((unsigned short*)(ws + WSKU_OFF))[tt] = f2bf(sw[tt]);
    } else if (tt < 294912) {
        int i = tt - 196608; int n = i / 192, k = i % 192;
        ((unsigned short*)(ws + WURL_OFF))[i] = (k < 160) ? f2bf(uw[n * 160 + k]) : 0;
    } else {
        int i = tt - 294912; int n = i / 192, k = i % 192;
        ((unsigned short*)(ws + WQRY_OFF))[i] = (k < 160) ? f2bf(qw[n * 160 + k]) : 0;
    }
}

// ---------------- K2: classify + slot allocation (block-aggregated) ----------
__global__ __launch_bounds__(256) void alloc_k(const int* __restrict__ et_a,
                                               float* __restrict__ out, char* ws) {
    __shared__ int s_wcnt[4][3];
    __shared__ int s_base[3];
    __shared__ int s_woff[4][3];
    const int t = threadIdx.x, lane = t & 63, wid = t >> 6;
    int p = blockIdx.x * 256 + t;
    int et = et_a[p];
    int br = (et >= 1 && et <= 3) ? 0 : (et == 4 ? 1 : (et == 5 ? 2 : -1));
    unsigned long long m0 = __ballot(br == 0);
    unsigned long long m1 = __ballot(br == 1);
    unsigned long long m2 = __ballot(br == 2);
    if (lane == 0) {
        s_wcnt[wid][0] = (int)__popcll(m0);
        s_wcnt[wid][1] = (int)__popcll(m1);
        s_wcnt[wid][2] = (int)__popcll(m2);
    }
    __syncthreads();
    if (t < 3) {
        int c0 = s_wcnt[0][t], c1 = s_wcnt[1][t], c2 = s_wcnt[2][t], c3 = s_wcnt[3][t];
        int tot = c0 + c1 + c2 + c3;
        s_base[t] = tot ? atomicAdd(&((int*)(ws + CUR_OFF))[t], tot) : 0;
        s_woff[0][t] = 0; s_woff[1][t] = c0; s_woff[2][t] = c0 + c1; s_woff[3][t] = c0 + c1 + c2;
    }
    __syncthreads();
    unsigned long long lt = (1ull << lane) - 1ull;
    int slot = -1;
    if (br == 0)      slot = s_base[0] + s_woff[wid][0] + (int)__popcll(m0 & lt);
    else if (br == 1) slot = s_base[1] + s_woff[wid][1] + (int)__popcll(m1 & lt);
    else if (br == 2) slot = s_base[2] + s_woff[wid][2] + (int)__popcll(m2 & lt);
    ((int*)(ws + SLOT_OFF))[p] = slot;
    if (slot >= 0) ((int*)(ws + POS_OFF))[br * NPOS + slot] = p;
    __builtin_nontemporal_store((et == 0) ? 1.0f : 0.0f, &out[OUT_MASK + p]);
}

// ---------------- K3: build bf16 input rows, 1 position per wave ------------
__device__ __forceinline__ float2 wmean_f8(const unsigned char* __restrict__ wt8,
                                           const int* __restrict__ wids, int lane) {
    float sx = 0.f, sy = 0.f;
    #pragma unroll
    for (int k = 0; k < 12; ++k) {
        unsigned int u = *reinterpret_cast<const unsigned short*>(
            wt8 + (size_t)wids[k] * 128 + 2 * lane);
        float2 v = upk2_fp8(u);
        sx += v.x; sy += v.y;
    }
    return make_float2(sx * F8_INV, sy * F8_INV);
}

__global__ __launch_bounds__(256) void build_k(
    const float* __restrict__ ev_t,
    const float* __restrict__ sku_t,  const float* __restrict__ cat_t,
    const float* __restrict__ price_t,const float* __restrict__ url_t,
    const int* __restrict__ et_a,     const int* __restrict__ sku_id,
    const int* __restrict__ url_id,   const int* __restrict__ cat_id,
    const int* __restrict__ price_id, const int* __restrict__ word_id,
    float* __restrict__ out, char* ws)
{
    const int t = threadIdx.x, lane = t & 63, wid = t >> 6;
    const int p = blockIdx.x * 4 + wid;         // one position per wave
    const int et = et_a[p];
    if (et == 0) {  // pad: zero output row (nontemporal: out is write-once)
        f32x4 z = {0.f, 0.f, 0.f, 0.f};
        float* orow = out + (size_t)p * 512;
        __builtin_nontemporal_store(z, reinterpret_cast<f32x4*>(&orow[lane * 8]));
        __builtin_nontemporal_store(z, reinterpret_cast<f32x4*>(&orow[lane * 8 + 4]));
        return;
    }
    const int slot = ((const int*)(ws + SLOT_OFF))[p];
    const unsigned char* wf8 = (const unsigned char*)(ws + WF8_OFF);
    const float* evr = ev_t + et * 32;
    if (et <= 3) {  // sku: [ev 0..32)[sku 32..160)[cat 160..224)[price 224..256)[word 256..384)
        __hip_bfloat16* X = (__hip_bfloat16*)(ws + XS_OFF + (size_t)slot * 768);
        if (lane < 16) st2(X + 2 * lane, ld2(evr + 2 * lane));
        const float* sr = sku_t + (size_t)sku_id[p] * 128;
        st2(X + 32 + 2 * lane, ld2(sr + 2 * lane));
        const float* crr = cat_t + (size_t)cat_id[p] * 64;
        if (lane < 32) st2(X + 160 + 2 * lane, ld2(crr + 2 * lane));
        const float* prr = price_t + (size_t)price_id[p] * 32;
        if (lane < 16) st2(X + 224 + 2 * lane, ld2(prr + 2 * lane));
        float2 w = wmean_f8(wf8, word_id + (size_t)p * 12, lane);
        st2(X + 256 + 2 * lane, w);
    } else if (et == 4) {  // url: [url 0..128)[ev 128..160)[pad 160..192)
        __hip_bfloat16* X = (__hip_bfloat16*)(ws + XU_OFF + (size_t)slot * 384);
        const float* ur = url_t + (size_t)url_id[p] * 128;
        st2(X + 2 * lane, ld2(ur + 2 * lane));
        if (lane < 16) st2(X + 128 + 2 * lane, ld2(evr + 2 * lane));
        if (lane < 16) st2(X + 160 + 2 * lane, make_float2(0.f, 0.f));
    } else {               // query: [ev 0..32)[word 32..160)[pad 160..192)
        __hip_bfloat16* X = (__hip_bfloat16*)(ws + XQ_OFF + (size_t)slot * 384);
        if (lane < 16) st2(X + 2 * lane, ld2(evr + 2 * lane));
        float2 w = wmean_f8(wf8, word_id + (size_t)p * 12, lane);
        st2(X + 32 + 2 * lane, w);
        if (lane < 16) st2(X + 160 + 2 * lane, make_float2(0.f, 0.f));
    }
}

// ---------------- K4: merged branch GEMMs  out[pos]=relu(X*W^T+b) -----------
// 128x128 tile, BK=64, 4 waves (2x2) x 64x64, mfma_f32_16x16x32_bf16.
// T2 swizzle: linear LDS dest, source pre-swizzled, reads XOR'd (rule #21).
// ny innermost + bijective XCD swizzle (m204); out stores nontemporal.
__global__ __launch_bounds__(256, 2) void gemm_all_k(
    const char* __restrict__ ws_c, const float* __restrict__ sku_b,
    const float* __restrict__ url_b, const float* __restrict__ qry_b,
    float* __restrict__ out)
{
    const int z = blockIdx.z;
    const int count = ((const int*)(ws_c + CUR_OFF))[z];
    const int nmt = (count + 127) >> 7;
    const int nwg = nmt * 4;
    const int orig = blockIdx.x;
    if (orig >= nwg) return;
    const int q8 = nwg >> 3, r8 = nwg & 7;
    const int xcd = orig & 7, idx = orig >> 3;
    const int wg = (xcd < r8 ? xcd * (q8 + 1) : r8 * (q8 + 1) + (xcd - r8) * q8) + idx;
    const int mt = wg >> 2;             // ny innermost: 4 consecutive wg share mt
    const int row0 = mt * 128;
    const int nc0  = (wg & 3) * 128;

    const char* arena; const char* Wb; const float* bias; const int* posm;
    int astride, nkt;
    if (z == 0) { arena = ws_c + XS_OFF; Wb = ws_c + WSKU_OFF; bias = sku_b;
                  posm = (const int*)(ws_c + POS_OFF);          astride = 768; nkt = 6; }
    else if (z == 1) { arena = ws_c + XU_OFF; Wb = ws_c + WURL_OFF; bias = url_b;
                  posm = (const int*)(ws_c + POS_OFF) + NPOS;   astride = 384; nkt = 3; }
    else       { arena = ws_c + XQ_OFF; Wb = ws_c + WQRY_OFF; bias = qry_b;
                  posm = (const int*)(ws_c + POS_OFF) + 2*NPOS; astride = 384; nkt = 3; }
    const int wstride = astride;

    __shared__ char lds[2][2][16384];   // [buf][A/B][128 rows x 128 B]

    const int t = threadIdx.x;
    const int lane = t & 63;
    const int wid  = t >> 6;
    const int wr = wid >> 1, wc = wid & 1;
    const int r = lane & 15, q = lane >> 4;

    auto stage = [&](int buf, int kt) {
        #pragma unroll
        for (int i = 0; i < 4; ++i) {
            int row = i * 32 + (t >> 3);
            int sb  = (t & 7) ^ (row & 7);
            const char* ga = arena + (size_t)(row0 + row) * astride + kt * 128 + sb * 16;
            __builtin_amdgcn_global_load_lds(AS1(ga), AS3(&lds[buf][0][i * 4096 + t * 16]), 16, 0, 0);
            const char* gb = Wb + (size_t)(nc0 + row) * wstride + kt * 128 + sb * 16;
            __builtin_amdgcn_global_load_lds(AS1(gb), AS3(&lds[buf][1][i * 4096 + t * 16]), 16, 0, 0);
        }
    };

    f32x4 acc[4][4];
    #pragma unroll
    for (int m = 0; m < 4; ++m)
        #pragma unroll
        for (int n = 0; n < 4; ++n)
            acc[m][n] = (f32x4){0.f, 0.f, 0.f, 0.f};

    stage(0, 0);
    __syncthreads();
    int cur = 0;
    for (int kt = 0; kt < nkt; ++kt) {
        if (kt + 1 < nkt) stage(cur ^ 1, kt + 1);
        #pragma unroll
        for (int kk = 0; kk < 2; ++kk) {
            bf16x8 af[4], bfr[4];
            #pragma unroll
            for (int m = 0; m < 4; ++m) {
                int arow = wr * 64 + m * 16 + r;
                af[m] = *reinterpret_cast<const bf16x8*>(
                    &lds[cur][0][arow * 128 + (((kk * 4 + q) ^ (r & 7)) * 16)]);
            }
            #pragma unroll
            for (int n = 0; n < 4; ++n) {
                int brow = wc * 64 + n * 16 + r;
                bfr[n] = *reinterpret_cast<const bf16x8*>(
                    &lds[cur][1][brow * 128 + (((kk * 4 + q) ^ (r & 7)) * 16)]);
            }
            #pragma unroll
            for (int m = 0; m < 4; ++m)
                #pragma unroll
                for (int n = 0; n < 4; ++n)
                    acc[m][n] = __builtin_amdgcn_mfma_f32_16x16x32_bf16(af[m], bfr[n], acc[m][n], 0, 0, 0);
        }
        __syncthreads();
        cur ^= 1;
    }

    float bv[4];
    #pragma unroll
    for (int n = 0; n < 4; ++n) bv[n] = bias[nc0 + wc * 64 + n * 16 + r];
    #pragma unroll
    for (int m = 0; m < 4; ++m) {
        #pragma unroll
        for (int j = 0; j < 4; ++j) {
            int rl = wr * 64 + m * 16 + q * 4 + j;
            int gr = row0 + rl;
            if (gr < count) {
                int pos = posm[gr];
                float* orow = out + (size_t)pos * 512 + nc0 + wc * 64;
                #pragma unroll
                for (int n = 0; n < 4; ++n)
                    __builtin_nontemporal_store(fmaxf(acc[m][n][j] + bv[n], 0.f),
                                                &orow[n * 16 + r]);
            }
        }
    }
}

// ---------------- host ----------------
extern "C" void kernel_launch(void* const* d_in, const int* in_sizes, int n_in,
                              void* d_out, int out_size, void* d_ws, size_t ws_size,
                              hipStream_t stream) {
    const float* ev_t    = (const float*)d_in[0];
    const float* word_t  = (const float*)d_in[1];
    const float* sku_t   = (const float*)d_in[2];
    const float* cat_t   = (const float*)d_in[3];
    const float* price_t = (const float*)d_in[4];
    const float* url_t   = (const float*)d_in[5];
    const float* sku_w   = (const float*)d_in[6];
    const float* sku_b   = (const float*)d_in[7];
    const float* url_w   = (const float*)d_in[8];
    const float* url_b   = (const float*)d_in[9];
    const float* query_w = (const float*)d_in[10];
    const float* query_b = (const float*)d_in[11];
    const int* event_type = (const int*)d_in[12];
    const int* sku_id     = (const int*)d_in[13];
    const int* url_id     = (const int*)d_in[14];
    const int* cat_id     = (const int*)d_in[15];
    const int* price_id   = (const int*)d_in[16];
    const int* word_id    = (const int*)d_in[17];

    char*  ws  = (char*)d_ws;
    float* out = (float*)d_out;

    prep_k<<<7786, 256, 0, stream>>>(sku_w, url_w, query_w, word_t, ws);
    alloc_k<<<256, 256, 0, stream>>>(event_type, out, ws);
    build_k<<<16384, 256, 0, stream>>>(ev_t, sku_t, cat_t, price_t, url_t,
                                       event_type, sku_id, url_id, cat_id, price_id,
                                       word_id, out, ws);
    dim3 gg(2048, 1, 3);
    gemm_all_k<<<gg, 256, 0, stream>>>(ws, sku_b, url_b, query_b, out);
}

// Round 8
// 86.637 us; speedup vs baseline: 2.1749x; 1.0710x over previous
//
#include <hip/hip_runtime.h>
#include <hip/hip_bf16.h>
#if !__has_builtin(__builtin_amdgcn_cvt_pk_fp8_f32) || !__has_builtin(__builtin_amdgcn_cvt_pk_f32_fp8)
#include <hip/hip_fp8.h>
#endif

// ---------------- workspace layout (bytes); ws_size ~1 GB ----------------
#define CUR_OFF   0          // int cur[3]
#define SLOT_OFF  1024       // int slot_of_pos[65536]
#define POS_OFF   263168     // int posm[3][65536]
#define WSKU_OFF  1049600    // fp8 [512][384] (x64)
#define WURL_OFF  1246208    // fp8 [512][256] (x64, cols 160..256 zero)
#define WQRY_OFF  1377280    // fp8 [512][256]
#define WF8_OFF   2097152    // fp8 word table [100000][128] (x64) = 12.8 MB
#define XS_OFF    16777216   // fp8 rows, stride 384 B, 65664 rows
#define XU_OFF    50331648   // fp8 rows, stride 256 B, 65664 rows
#define XQ_OFF    68157440   // fp8 rows, stride 256 B, 65664 rows (end ~85 MB)

#define NPOS      65536
#define OUT_MASK  33554432   // 65536*512
#define F8_SCALE  64.0f
#define INV4096   (1.0f / 4096.0f)

typedef __attribute__((ext_vector_type(4))) float f32x4;
typedef __attribute__((ext_vector_type(2))) float f32x2;
typedef __attribute__((ext_vector_type(2))) unsigned int u32x2;

__device__ __forceinline__ unsigned short f2bf(float x) {
    unsigned int u = __float_as_uint(x);
    return (unsigned short)((u + 0x7fffu + ((u >> 16) & 1u)) >> 16);
}
__device__ __forceinline__ float2 ld2(const float* p) {
    return *reinterpret_cast<const float2*>(p);
}

// fp8 e4m3 (OCP) pack/unpack
__device__ __forceinline__ unsigned int pk2_f8(float a, float b) {
#if __has_builtin(__builtin_amdgcn_cvt_pk_fp8_f32)
    return __builtin_amdgcn_cvt_pk_fp8_f32(a, b, 0u, false);
#else
    __hip_fp8_e4m3 fa(a), fb(b);
    return (unsigned int)fa.__x | ((unsigned int)fb.__x << 8);
#endif
}
__device__ __forceinline__ unsigned int pk4_f8(float a, float b, float c, float d) {
#if __has_builtin(__builtin_amdgcn_cvt_pk_fp8_f32)
    unsigned int v = 0;
    v = __builtin_amdgcn_cvt_pk_fp8_f32(a, b, v, false);
    v = __builtin_amdgcn_cvt_pk_fp8_f32(c, d, v, true);
    return v;
#else
    return pk2_f8(a, b) | (pk2_f8(c, d) << 16);
#endif
}
__device__ __forceinline__ float2 upk2_f8(unsigned int u) {
#if __has_builtin(__builtin_amdgcn_cvt_pk_f32_fp8)
    f32x2 r = __builtin_amdgcn_cvt_pk_f32_fp8(u, false);
    return make_float2(r.x, r.y);
#else
    __hip_fp8_e4m3 fa, fb;
    fa.__x = (unsigned char)(u & 0xff);
    fb.__x = (unsigned char)((u >> 8) & 0xff);
    return make_float2((float)fa, (float)fb);
#endif
}
__device__ __forceinline__ void st_f8x2(unsigned char* d, float a, float b) {
    *reinterpret_cast<unsigned short*>(d) = (unsigned short)(pk2_f8(a, b) & 0xffffu);
}

#define AS1(p) ((const __attribute__((address_space(1))) void*)(p))
#define AS3(p) ((__attribute__((address_space(3))) void*)(p))

// ---- K1: word table f32->fp8(x64) + weights f32->fp8(x64) + cursor zero ----
// blocks [0,6250): word table (12.8M elems, 8/thread)
// blocks [6250,8042): weights (458752 elems, 1/thread) + cursor zero
__global__ __launch_bounds__(256) void prep_k(const float* __restrict__ sw,
                                              const float* __restrict__ uw,
                                              const float* __restrict__ qw,
                                              const float* __restrict__ word_t,
                                              char* ws) {
    const int b = blockIdx.x, t = threadIdx.x;
    if (b < 6250) {
        size_t i = ((size_t)b * 256 + t) * 8;
        f32x4 v0 = *reinterpret_cast<const f32x4*>(word_t + i);
        f32x4 v1 = *reinterpret_cast<const f32x4*>(word_t + i + 4);
        u32x2 pk;
        pk.x = pk4_f8(v0.x * F8_SCALE, v0.y * F8_SCALE, v0.z * F8_SCALE, v0.w * F8_SCALE);
        pk.y = pk4_f8(v1.x * F8_SCALE, v1.y * F8_SCALE, v1.z * F8_SCALE, v1.w * F8_SCALE);
        *reinterpret_cast<u32x2*>((unsigned char*)(ws + WF8_OFF) + i) = pk;
        return;
    }
    int tt = (b - 6250) * 256 + t;   // 458752 total
    if (tt < 3) ((int*)(ws + CUR_OFF))[tt] = 0;
    if (tt < 196608) {
        ((unsigned char*)(ws + WSKU_OFF))[tt] =
            (unsigned char)(pk2_f8(sw[tt] * F8_SCALE, 0.f) & 0xffu);
    } else if (tt < 327680) {
        int i = tt - 196608; int n = i >> 8, k = i & 255;
        ((unsigned char*)(ws + WURL_OFF))[i] = (k < 160)
            ? (unsigned char)(pk2_f8(uw[n * 160 + k] * F8_SCALE, 0.f) & 0xffu) : 0;
    } else {
        int i = tt - 327680; int n = i >> 8, k = i & 255;
        ((unsigned char*)(ws + WQRY_OFF))[i] = (k < 160)
            ? (unsigned char)(pk2_f8(qw[n * 160 + k] * F8_SCALE, 0.f) & 0xffu) : 0;
    }
}

// ---------------- K2: classify + slot allocation (block-aggregated) ----------
__global__ __launch_bounds__(256) void alloc_k(const int* __restrict__ et_a,
                                               float* __restrict__ out, char* ws) {
    __shared__ int s_wcnt[4][3];
    __shared__ int s_base[3];
    __shared__ int s_woff[4][3];
    const int t = threadIdx.x, lane = t & 63, wid = t >> 6;
    int p = blockIdx.x * 256 + t;
    int et = et_a[p];
    int br = (et >= 1 && et <= 3) ? 0 : (et == 4 ? 1 : (et == 5 ? 2 : -1));
    unsigned long long m0 = __ballot(br == 0);
    unsigned long long m1 = __ballot(br == 1);
    unsigned long long m2 = __ballot(br == 2);
    if (lane == 0) {
        s_wcnt[wid][0] = (int)__popcll(m0);
        s_wcnt[wid][1] = (int)__popcll(m1);
        s_wcnt[wid][2] = (int)__popcll(m2);
    }
    __syncthreads();
    if (t < 3) {
        int c0 = s_wcnt[0][t], c1 = s_wcnt[1][t], c2 = s_wcnt[2][t], c3 = s_wcnt[3][t];
        int tot = c0 + c1 + c2 + c3;
        s_base[t] = tot ? atomicAdd(&((int*)(ws + CUR_OFF))[t], tot) : 0;
        s_woff[0][t] = 0; s_woff[1][t] = c0; s_woff[2][t] = c0 + c1; s_woff[3][t] = c0 + c1 + c2;
    }
    __syncthreads();
    unsigned long long lt = (1ull << lane) - 1ull;
    int slot = -1;
    if (br == 0)      slot = s_base[0] + s_woff[wid][0] + (int)__popcll(m0 & lt);
    else if (br == 1) slot = s_base[1] + s_woff[wid][1] + (int)__popcll(m1 & lt);
    else if (br == 2) slot = s_base[2] + s_woff[wid][2] + (int)__popcll(m2 & lt);
    ((int*)(ws + SLOT_OFF))[p] = slot;
    if (slot >= 0) ((int*)(ws + POS_OFF))[br * NPOS + slot] = p;
    __builtin_nontemporal_store((et == 0) ? 1.0f : 0.0f, &out[OUT_MASK + p]);
}

// ---------------- K3: build fp8 input rows (x64 domain), 1 pos/wave ---------
__device__ __forceinline__ float2 wsum_f8(const unsigned char* __restrict__ wt8,
                                          const int* __restrict__ wids, int lane) {
    float sx = 0.f, sy = 0.f;
    #pragma unroll
    for (int k = 0; k < 12; ++k) {
        unsigned int u = *reinterpret_cast<const unsigned short*>(
            wt8 + (size_t)wids[k] * 128 + 2 * lane);
        float2 v = upk2_f8(u);
        sx += v.x; sy += v.y;
    }
    const float inv = 1.0f / 12.0f;      // stays in x64 domain
    return make_float2(sx * inv, sy * inv);
}

__global__ __launch_bounds__(256) void build_k(
    const float* __restrict__ ev_t,
    const float* __restrict__ sku_t,  const float* __restrict__ cat_t,
    const float* __restrict__ price_t,const float* __restrict__ url_t,
    const int* __restrict__ et_a,     const int* __restrict__ sku_id,
    const int* __restrict__ url_id,   const int* __restrict__ cat_id,
    const int* __restrict__ price_id, const int* __restrict__ word_id,
    float* __restrict__ out, char* ws)
{
    const int t = threadIdx.x, lane = t & 63, wid = t >> 6;
    const int p = blockIdx.x * 4 + wid;
    const int et = et_a[p];
    if (et == 0) {  // pad: zero output row
        f32x4 z = {0.f, 0.f, 0.f, 0.f};
        float* orow = out + (size_t)p * 512;
        __builtin_nontemporal_store(z, reinterpret_cast<f32x4*>(&orow[lane * 8]));
        __builtin_nontemporal_store(z, reinterpret_cast<f32x4*>(&orow[lane * 8 + 4]));
        return;
    }
    const int slot = ((const int*)(ws + SLOT_OFF))[p];
    const unsigned char* wf8 = (const unsigned char*)(ws + WF8_OFF);
    const float* evr = ev_t + et * 32;
    if (et <= 3) {  // sku row: [ev 0..32)[sku 32..160)[cat 160..224)[price 224..256)[word 256..384)
        unsigned char* X = (unsigned char*)(ws + XS_OFF) + (size_t)slot * 384;
        if (lane < 16) { float2 e = ld2(evr + 2 * lane);
                         st_f8x2(X + 2 * lane, e.x * F8_SCALE, e.y * F8_SCALE); }
        const float* sr = sku_t + (size_t)sku_id[p] * 128;
        { float2 s = ld2(sr + 2 * lane);
          st_f8x2(X + 32 + 2 * lane, s.x * F8_SCALE, s.y * F8_SCALE); }
        if (lane < 32) { const float* cr = cat_t + (size_t)cat_id[p] * 64;
                         float2 c = ld2(cr + 2 * lane);
                         st_f8x2(X + 160 + 2 * lane, c.x * F8_SCALE, c.y * F8_SCALE); }
        if (lane < 16) { const float* pr = price_t + (size_t)price_id[p] * 32;
                         float2 v = ld2(pr + 2 * lane);
                         st_f8x2(X + 224 + 2 * lane, v.x * F8_SCALE, v.y * F8_SCALE); }
        float2 w = wsum_f8(wf8, word_id + (size_t)p * 12, lane);
        st_f8x2(X + 256 + 2 * lane, w.x, w.y);
    } else if (et == 4) {  // url row: [url 0..128)[ev 128..160)[pad 160..256)
        unsigned char* X = (unsigned char*)(ws + XU_OFF) + (size_t)slot * 256;
        const float* ur = url_t + (size_t)url_id[p] * 128;
        { float2 u = ld2(ur + 2 * lane);
          st_f8x2(X + 2 * lane, u.x * F8_SCALE, u.y * F8_SCALE); }
        if (lane < 16) { float2 e = ld2(evr + 2 * lane);
                         st_f8x2(X + 128 + 2 * lane, e.x * F8_SCALE, e.y * F8_SCALE); }
        if (lane < 48) *reinterpret_cast<unsigned short*>(X + 160 + 2 * lane) = 0;
    } else {               // query row: [ev 0..32)[word 32..160)[pad 160..256)
        unsigned char* X = (unsigned char*)(ws + XQ_OFF) + (size_t)slot * 256;
        if (lane < 16) { float2 e = ld2(evr + 2 * lane);
                         st_f8x2(X + 2 * lane, e.x * F8_SCALE, e.y * F8_SCALE); }
        float2 w = wsum_f8(wf8, word_id + (size_t)p * 12, lane);
        st_f8x2(X + 32 + 2 * lane, w.x, w.y);
        if (lane < 48) *reinterpret_cast<unsigned short*>(X + 160 + 2 * lane) = 0;
    }
}

// ---------------- K4: merged fp8 branch GEMMs  out[pos]=relu(X*W^T/4096+b) --
// 128x128 tile, BK=128 (bytes), 4 waves (2x2) x 64x64, mfma_f32_16x16x32_fp8_fp8.
// T2 swizzle on 16B units: linear LDS dest, source pre-swizzled, reads XOR'd.
__global__ __launch_bounds__(256, 2) void gemm_all_k(
    const char* __restrict__ ws_c, const float* __restrict__ sku_b,
    const float* __restrict__ url_b, const float* __restrict__ qry_b,
    float* __restrict__ out)
{
    const int z = blockIdx.z;
    const int count = ((const int*)(ws_c + CUR_OFF))[z];
    const int nmt = (count + 127) >> 7;
    const int nwg = nmt * 4;
    const int orig = blockIdx.x;
    if (orig >= nwg) return;
    const int q8 = nwg >> 3, r8 = nwg & 7;
    const int xcd = orig & 7, idx = orig >> 3;
    const int wg = (xcd < r8 ? xcd * (q8 + 1) : r8 * (q8 + 1) + (xcd - r8) * q8) + idx;
    const int mt = wg >> 2;
    const int row0 = mt * 128;
    const int nc0  = (wg & 3) * 128;

    const char* arena; const char* Wb; const float* bias; const int* posm;
    int astride, nkt;
    if (z == 0) { arena = ws_c + XS_OFF; Wb = ws_c + WSKU_OFF; bias = sku_b;
                  posm = (const int*)(ws_c + POS_OFF);          astride = 384; nkt = 3; }
    else if (z == 1) { arena = ws_c + XU_OFF; Wb = ws_c + WURL_OFF; bias = url_b;
                  posm = (const int*)(ws_c + POS_OFF) + NPOS;   astride = 256; nkt = 2; }
    else       { arena = ws_c + XQ_OFF; Wb = ws_c + WQRY_OFF; bias = qry_b;
                  posm = (const int*)(ws_c + POS_OFF) + 2*NPOS; astride = 256; nkt = 2; }

    __shared__ char lds[2][2][16384];   // [buf][A/B][128 rows x 128 B]

    const int t = threadIdx.x;
    const int lane = t & 63;
    const int wid  = t >> 6;
    const int wr = wid >> 1, wc = wid & 1;
    const int r = lane & 15, q = lane >> 4;

    auto stage = [&](int buf, int kt) {
        #pragma unroll
        for (int i = 0; i < 4; ++i) {
            int row = i * 32 + (t >> 3);
            int sb  = (t & 7) ^ (row & 7);
            const char* ga = arena + (size_t)(row0 + row) * astride + kt * 128 + sb * 16;
            __builtin_amdgcn_global_load_lds(AS1(ga), AS3(&lds[buf][0][i * 4096 + t * 16]), 16, 0, 0);
            const char* gb = Wb + (size_t)(nc0 + row) * astride + kt * 128 + sb * 16;
            __builtin_amdgcn_global_load_lds(AS1(gb), AS3(&lds[buf][1][i * 4096 + t * 16]), 16, 0, 0);
        }
    };

    f32x4 acc[4][4];
    #pragma unroll
    for (int m = 0; m < 4; ++m)
        #pragma unroll
        for (int n = 0; n < 4; ++n)
            acc[m][n] = (f32x4){0.f, 0.f, 0.f, 0.f};

    stage(0, 0);
    __syncthreads();
    int cur = 0;
    for (int kt = 0; kt < nkt; ++kt) {
        if (kt + 1 < nkt) stage(cur ^ 1, kt + 1);
        #pragma unroll
        for (int kk = 0; kk < 4; ++kk) {       // K=32 fp8 per kk
            const int u  = kk * 2 + (q >> 1);  // 16B unit 0..7
            const int wo = (q & 1) * 8;        // within-unit byte offset
            long af[4], bfr[4];
            #pragma unroll
            for (int m = 0; m < 4; ++m) {
                int arow = wr * 64 + m * 16 + r;
                af[m] = *reinterpret_cast<const long*>(
                    &lds[cur][0][arow * 128 + ((u ^ (arow & 7)) << 4) + wo]);
            }
            #pragma unroll
            for (int n = 0; n < 4; ++n) {
                int brow = wc * 64 + n * 16 + r;
                bfr[n] = *reinterpret_cast<const long*>(
                    &lds[cur][1][brow * 128 + ((u ^ (brow & 7)) << 4) + wo]);
            }
            #pragma unroll
            for (int m = 0; m < 4; ++m)
                #pragma unroll
                for (int n = 0; n < 4; ++n)
                    acc[m][n] = __builtin_amdgcn_mfma_f32_16x16x32_fp8_fp8(af[m], bfr[n], acc[m][n], 0, 0, 0);
        }
        __syncthreads();
        cur ^= 1;
    }

    float bv[4];
    #pragma unroll
    for (int n = 0; n < 4; ++n) bv[n] = bias[nc0 + wc * 64 + n * 16 + r];
    #pragma unroll
    for (int m = 0; m < 4; ++m) {
        #pragma unroll
        for (int j = 0; j < 4; ++j) {
            int rl = wr * 64 + m * 16 + q * 4 + j;
            int gr = row0 + rl;
            if (gr < count) {
                int pos = posm[gr];
                float* orow = out + (size_t)pos * 512 + nc0 + wc * 64;
                #pragma unroll
                for (int n = 0; n < 4; ++n)
                    __builtin_nontemporal_store(
                        fmaxf(acc[m][n][j] * INV4096 + bv[n], 0.f), &orow[n * 16 + r]);
            }
        }
    }
}

// ---------------- host ----------------
extern "C" void kernel_launch(void* const* d_in, const int* in_sizes, int n_in,
                              void* d_out, int out_size, void* d_ws, size_t ws_size,
                              hipStream_t stream) {
    const float* ev_t    = (const float*)d_in[0];
    const float* word_t  = (const float*)d_in[1];
    const float* sku_t   = (const float*)d_in[2];
    const float* cat_t   = (const float*)d_in[3];
    const float* price_t = (const float*)d_in[4];
    const float* url_t   = (const float*)d_in[5];
    const float* sku_w   = (const float*)d_in[6];
    const float* sku_b   = (const float*)d_in[7];
    const float* url_w   = (const float*)d_in[8];
    const float* url_b   = (const float*)d_in[9];
    const float* query_w = (const float*)d_in[10];
    const float* query_b = (const float*)d_in[11];
    const int* event_type = (const int*)d_in[12];
    const int* sku_id     = (const int*)d_in[13];
    const int* url_id     = (const int*)d_in[14];
    const int* cat_id     = (const int*)d_in[15];
    const int* price_id   = (const int*)d_in[16];
    const int* word_id    = (const int*)d_in[17];

    char*  ws  = (char*)d_ws;
    float* out = (float*)d_out;

    prep_k<<<8042, 256, 0, stream>>>(sku_w, url_w, query_w, word_t, ws);
    alloc_k<<<256, 256, 0, stream>>>(event_type, out, ws);
    build_k<<<16384, 256, 0, stream>>>(ev_t, sku_t, cat_t, price_t, url_t,
                                       event_type, sku_id, url_id, cat_id, price_id,
                                       word_id, out, ws);
    dim3 gg(2048, 1, 3);
    gemm_all_k<<<gg, 256, 0, stream>>>(ws, sku_b, url_b, query_b, out);
}